// Round 4
// baseline (1784.140 us; speedup 1.0000x reference)
//
#include <hip/hip_runtime.h>
#include <hip/hip_bf16.h>

#define HID 128
#define NN 50000
#define NR 500
#define NE 625000
#define LRELU 0.01f

typedef __hip_bfloat16 bf16;

__device__ __forceinline__ float b2f(bf16 v) { return __bfloat162float(v); }
__device__ __forceinline__ bf16 f2b(float v) { return __float2bfloat16(v); }

__device__ __forceinline__ float san(float v) {
    return (v == v && v > -1e30f && v < 1e30f) ? v : 0.f;
}

// flag-driven load/store: f32==1 -> buffer is float32, else bf16
__device__ __forceinline__ float ldf(const void* p, int i, int f32) {
    return f32 ? ((const float*)p)[i] : b2f(((const bf16*)p)[i]);
}
__device__ __forceinline__ void stf(void* p, int i, float v, int f32) {
    if (f32) ((float*)p)[i] = v;
    else ((bf16*)p)[i] = f2b(v);
}

__device__ __forceinline__ float waveReduce(float v) {
#pragma unroll
    for (int off = 32; off > 0; off >>= 1) v += __shfl_down(v, off, 64);
    return v;
}

__device__ __forceinline__ int clampi(int v, int hi) {
    return v < 0 ? 0 : (v >= hi ? hi - 1 : v);
}

__device__ __forceinline__ int idx_at(const int* p, int i, int is64) {
    return p[is64 ? (2 * i) : i];
}

// ---------------------------------------------------------------- dtype detectors
__global__ void detect_float(const unsigned int* __restrict__ w, int M, int* __restrict__ flag) {
    __shared__ int sb[64], sf[64];
    int K = M >> 1;
    if (K > 4096) K = 4096;
    int bv = 0, fv = 0;
    for (int i = threadIdx.x; i < K; i += 64) {
        unsigned int x = w[i];
        unsigned int lo = x & 0xFFFFu, hi = x >> 16;
        if (lo == 0u) {
            if (hi) fv++;
        } else {
            unsigned int e = (lo >> 7) & 0xFFu;
            if (e >= 90u && e <= 160u) bv++;
            else fv++;
        }
    }
    sb[threadIdx.x] = bv; sf[threadIdx.x] = fv;
    __syncthreads();
    if (threadIdx.x == 0) {
        int B = 0, F = 0;
        for (int i = 0; i < 64; ++i) { B += sb[i]; F += sf[i]; }
        *flag = (F > B) ? 1 : 0;
    }
}

__global__ void detect_idx(const int* __restrict__ p, int* __restrict__ flag) {
    if (threadIdx.x == 0) {
        int o = 0;
        for (int i = 0; i < 64; ++i) o |= p[2 * i + 1];
        *flag = (o == 0) ? 1 : 0;
    }
}

// ---------------------------------------------------------------- BatchNorm over r
__global__ void bn_kernel(const void* __restrict__ r, const void* __restrict__ gamma,
                          const void* __restrict__ beta, const int* __restrict__ flags,
                          float* __restrict__ rnorm, void* __restrict__ out_base) {
    const int fr = flags[1], fg = flags[14], fb = flags[15], fo = flags[0];
    int h = threadIdx.x;
    float s = 0.f, ss = 0.f;
    for (int i = 0; i < NR; ++i) {
        float v = ldf(r, i * HID + h, fr);
        s += v; ss += v * v;
    }
    float mu = s / NR;
    float var = ss / NR - mu * mu;
    if (var < 0.f) var = 0.f;
    float sc = ldf(gamma, h, fg) * rsqrtf(var + 1e-5f);
    float be = ldf(beta, h, fb);
    const int off = NN * HID;  // out_r element offset within d_out
    for (int i = 0; i < NR; ++i) {
        float v = san((ldf(r, i * HID + h, fr) - mu) * sc + be);
        rnorm[i * HID + h] = v;
        stf(out_base, off + i * HID + h, v, fo);
    }
}

// ---------------------------------------------------------------- edge-constant vectors
__global__ void precomp_kernel(const void* __restrict__ Wmatt, const void* __restrict__ bmatt,
                               const void* __restrict__ qc,
                               const void* __restrict__ Wxatt, const void* __restrict__ bxatt,
                               const void* __restrict__ fq, const int* __restrict__ flags,
                               float* __restrict__ cmatt, float* __restrict__ cxatt) {
    __shared__ float qcs[HID], fqs[HID];
    const int fWm = flags[8], fbm = flags[9], fqc = flags[2];
    const int fWx = flags[11], fbx = flags[12], ffq = flags[3];
    int h = threadIdx.x;
    qcs[h] = ldf(qc, h, fqc);
    fqs[h] = ldf(fq, h, ffq);
    __syncthreads();
    float a = ldf(bmatt, h, fbm), b = ldf(bxatt, h, fbx);
    for (int k = 0; k < HID; ++k) {
        a += ldf(Wmatt, h * 2 * HID + HID + k, fWm) * qcs[k];
        b += ldf(Wxatt, h * 2 * HID + HID + k, fWx) * fqs[k];
    }
    cmatt[h] = san(a);
    cxatt[h] = san(b);
}

// ---------------------------------------------------------------- Rm
__global__ void rm_kernel(const void* __restrict__ Wmess, const void* __restrict__ bmess,
                          const int* __restrict__ flags,
                          const float* __restrict__ rnorm, float* __restrict__ Rm) {
    __shared__ float rl[HID];
    const int fW = flags[6], fb = flags[7];
    int rel = blockIdx.x, h = threadIdx.x;
    rl[h] = rnorm[rel * HID + h];
    __syncthreads();
    float acc = ldf(bmess, h, fb);
    for (int k = 0; k < HID; ++k)
        acc += ldf(Wmess, h * 2 * HID + HID + k, fW) * rl[k];
    Rm[rel * HID + h] = san(acc);
}

// ---------------------------------------------------------------- Xm
__global__ void xm_kernel(const void* __restrict__ x, const void* __restrict__ Wmess,
                          const int* __restrict__ flags, bf16* __restrict__ Xmb) {
    __shared__ bf16 At[HID * 129];
    __shared__ float mL[HID * 8];
    const int fx = flags[0], fW = flags[6];
    int tid = threadIdx.x;
    for (int idx = tid; idx < HID * HID; idx += blockDim.x) {
        int h = idx >> 7, k = idx & 127;
        At[k * 129 + h] = f2b(ldf(Wmess, h * 2 * HID + k, fW));
    }
    int ngroups = NN >> 3;
    for (int g = blockIdx.x; g < ngroups; g += gridDim.x) {
        __syncthreads();
#pragma unroll
        for (int t = 0; t < 8; ++t)
            mL[tid * 8 + t] = ldf(x, (g * 8 + t) * HID + tid, fx);
        __syncthreads();
        float acc[8] = {0.f, 0.f, 0.f, 0.f, 0.f, 0.f, 0.f, 0.f};
#pragma unroll 4
        for (int k = 0; k < HID; ++k) {
            float a = b2f(At[k * 129 + tid]);
            float4 m0 = *(const float4*)&mL[k * 8];
            float4 m1 = *(const float4*)&mL[k * 8 + 4];
            acc[0] += a * m0.x; acc[1] += a * m0.y; acc[2] += a * m0.z; acc[3] += a * m0.w;
            acc[4] += a * m1.x; acc[5] += a * m1.y; acc[6] += a * m1.z; acc[7] += a * m1.w;
        }
#pragma unroll
        for (int t = 0; t < 8; ++t)
            Xmb[(g * 8 + t) * HID + tid] = f2b(san(acc[t]));
    }
}

// ---------------------------------------------------------------- edge logits
__global__ void edge_coeff_kernel(const bf16* __restrict__ Xmb, const float* __restrict__ Rm,
                                  const void* __restrict__ Wmatt, const float* __restrict__ cmatt,
                                  const void* __restrict__ maw,
                                  const int* __restrict__ ei, const int* __restrict__ ea,
                                  const int* __restrict__ flags,
                                  float* __restrict__ coeff) {
    __shared__ bf16 At[HID * 129];
    __shared__ float mL[HID * 8];
    __shared__ float redL[16];
    const int fWm = flags[8], fmw = flags[10];
    const int is64e = flags[4], is64a = flags[5];
    int tid = threadIdx.x;
    for (int idx = tid; idx < HID * HID; idx += blockDim.x) {
        int h = idx >> 7, k = idx & 127;
        At[k * 129 + h] = f2b(ldf(Wmatt, h * 2 * HID + k, fWm));
    }
    float mawh = ldf(maw, tid, fmw);
    float ch = cmatt[tid];
    int wave = tid >> 6;
    int ngroups = NE >> 3;
    for (int g = blockIdx.x; g < ngroups; g += gridDim.x) {
        __syncthreads();
#pragma unroll
        for (int t = 0; t < 8; ++t) {
            int e = g * 8 + t;
            int head = clampi(idx_at(ei, e, is64e), NN);
            int rel  = clampi(idx_at(ea, e, is64a), NR);
            mL[tid * 8 + t] = tanhf(san(b2f(Xmb[head * HID + tid]) + Rm[rel * HID + tid]));
        }
        __syncthreads();
        float acc[8] = {0.f, 0.f, 0.f, 0.f, 0.f, 0.f, 0.f, 0.f};
#pragma unroll 4
        for (int k = 0; k < HID; ++k) {
            float a = b2f(At[k * 129 + tid]);
            float4 m0 = *(const float4*)&mL[k * 8];
            float4 m1 = *(const float4*)&mL[k * 8 + 4];
            acc[0] += a * m0.x; acc[1] += a * m0.y; acc[2] += a * m0.z; acc[3] += a * m0.w;
            acc[4] += a * m1.x; acc[5] += a * m1.y; acc[6] += a * m1.z; acc[7] += a * m1.w;
        }
#pragma unroll
        for (int t = 0; t < 8; ++t) {
            float v = acc[t] + ch;
            float c = mawh * (v > 0.f ? v : LRELU * v);
            c = waveReduce(c);
            if ((tid & 63) == 0) redL[wave * 8 + t] = c;
        }
        __syncthreads();
        if (tid < 8) coeff[g * 8 + tid] = san(redL[tid] + redL[8 + tid]);
    }
}

// ---------------------------------------------------------------- CSR build
__global__ void count_kernel(const int* __restrict__ ei, const int* __restrict__ flags,
                             int* __restrict__ counts) {
    const int is64e = flags[4];
    for (int e = blockIdx.x * blockDim.x + threadIdx.x; e < NE; e += gridDim.x * blockDim.x) {
        int tail = clampi(idx_at(ei, NE + e, is64e), NN);
        atomicAdd(&counts[tail], 1);
    }
}

__global__ void scan_kernel(const int* __restrict__ counts, int* __restrict__ offs) {
    __shared__ int buf[1024];
    __shared__ int carry;
    int t = threadIdx.x;
    if (t == 0) carry = 0;
    __syncthreads();
    for (int base = 0; base < NN; base += 1024) {
        int v = (base + t < NN) ? counts[base + t] : 0;
        buf[t] = v;
        __syncthreads();
        for (int off = 1; off < 1024; off <<= 1) {
            int add = (t >= off) ? buf[t - off] : 0;
            __syncthreads();
            buf[t] += add;
            __syncthreads();
        }
        if (base + t < NN) offs[base + t] = carry + buf[t] - v;
        __syncthreads();
        if (t == 0) carry += buf[1023];
        __syncthreads();
    }
    if (t == 0) offs[NN] = carry;
}

__global__ void cursor_kernel(const int* __restrict__ offs, int* __restrict__ cursor) {
    int i = blockIdx.x * blockDim.x + threadIdx.x;
    if (i < NN) cursor[i] = offs[i];
}

__global__ void scatter_kernel(const int* __restrict__ ei, const int* __restrict__ flags,
                               int* __restrict__ cursor, int* __restrict__ eids) {
    const int is64e = flags[4];
    for (int e = blockIdx.x * blockDim.x + threadIdx.x; e < NE; e += gridDim.x * blockDim.x) {
        int tail = clampi(idx_at(ei, NE + e, is64e), NN);
        int pos = atomicAdd(&cursor[tail], 1);
        if (pos >= 0 && pos < NE) eids[pos] = e;
    }
}

// ---------------------------------------------------------------- node softmax + aggregation
__global__ void node_aggr_kernel(const bf16* __restrict__ Xmb, const float* __restrict__ Rm,
                                 const int* __restrict__ ei, const int* __restrict__ ea,
                                 const int* __restrict__ flags,
                                 const int* __restrict__ offs, const int* __restrict__ eids,
                                 const float* __restrict__ coeff, bf16* __restrict__ smb) {
    int n = blockIdx.x;
    int h = threadIdx.x;
    int s = offs[n], en = offs[n + 1];
    const int is64e = flags[4], is64a = flags[5];
    float m = -INFINITY;
    for (int i = s; i < en; ++i) m = fmaxf(m, coeff[eids[i]]);
    float l = 0.f;
    for (int i = s; i < en; ++i) l += expf(coeff[eids[i]] - m);
    float inv = 1.f / (l + 1e-16f);
    float acc = 0.f;
    for (int i = s; i < en; ++i) {
        int e = eids[i];
        int head = clampi(idx_at(ei, e, is64e), NN);
        int rel  = clampi(idx_at(ea, e, is64a), NR);
        float w = expf(coeff[e] - m) * inv;
        acc += w * tanhf(san(b2f(Xmb[head * HID + h]) + Rm[rel * HID + h]));
    }
    smb[n * HID + h] = f2b(san(acc));
}

// ---------------------------------------------------------------- node gating
__global__ void gate_kernel(const void* __restrict__ x, const bf16* __restrict__ smb,
                            const void* __restrict__ Wxatt, const float* __restrict__ cxatt,
                            const void* __restrict__ xaw, const int* __restrict__ flags,
                            void* __restrict__ outx) {
    __shared__ bf16 At[HID * 129];
    __shared__ float mL[HID * 8];
    __shared__ float redL[16];
    __shared__ float wL[8];
    const int fx = flags[0], fWx = flags[11], fxw = flags[13], fo = flags[0];
    int tid = threadIdx.x;
    for (int idx = tid; idx < HID * HID; idx += blockDim.x) {
        int h = idx >> 7, k = idx & 127;
        At[k * 129 + h] = f2b(ldf(Wxatt, h * 2 * HID + k, fWx));
    }
    float xawh = ldf(xaw, tid, fxw);
    float ch = cxatt[tid];
    int wave = tid >> 6;
    int ngroups = NN >> 2;
    for (int g = blockIdx.x; g < ngroups; g += gridDim.x) {
        __syncthreads();
#pragma unroll
        for (int t4 = 0; t4 < 4; ++t4) {
            int n = g * 4 + t4;
            mL[tid * 8 + t4 * 2]     = ldf(x, n * HID + tid, fx);
            mL[tid * 8 + t4 * 2 + 1] = b2f(smb[n * HID + tid]);
        }
        __syncthreads();
        float acc[8] = {0.f, 0.f, 0.f, 0.f, 0.f, 0.f, 0.f, 0.f};
#pragma unroll 4
        for (int k = 0; k < HID; ++k) {
            float a = b2f(At[k * 129 + tid]);
            float4 m0 = *(const float4*)&mL[k * 8];
            float4 m1 = *(const float4*)&mL[k * 8 + 4];
            acc[0] += a * m0.x; acc[1] += a * m0.y; acc[2] += a * m0.z; acc[3] += a * m0.w;
            acc[4] += a * m1.x; acc[5] += a * m1.y; acc[6] += a * m1.z; acc[7] += a * m1.w;
        }
#pragma unroll
        for (int t = 0; t < 8; ++t) {
            float v = acc[t] + ch;
            float c = xawh * (v > 0.f ? v : LRELU * v);
            c = waveReduce(c);
            if ((tid & 63) == 0) redL[wave * 8 + t] = c;
        }
        __syncthreads();
        if (tid < 4) {
            float c0 = san(redL[2 * tid] + redL[8 + 2 * tid]);
            float c1 = san(redL[2 * tid + 1] + redL[8 + 2 * tid + 1]);
            float mm = fmaxf(c0, c1);
            float e0 = expf(c0 - mm), e1 = expf(c1 - mm);
            float inv = 1.f / (e0 + e1);
            wL[2 * tid]     = e0 * inv;
            wL[2 * tid + 1] = e1 * inv;
        }
        __syncthreads();
#pragma unroll
        for (int t4 = 0; t4 < 4; ++t4) {
            int n = g * 4 + t4;
            float xv = mL[tid * 8 + 2 * t4];
            float sv = mL[tid * 8 + 2 * t4 + 1];
            stf(outx, n * HID + tid, san(wL[2 * t4] * xv + wL[2 * t4 + 1] * sv), fo);
        }
    }
}

extern "C" void kernel_launch(void* const* d_in, const int* in_sizes, int n_in,
                              void* d_out, int out_size, void* d_ws, size_t ws_size,
                              hipStream_t stream) {
    const void* x     = d_in[0];
    const void* r     = d_in[1];
    const void* qc    = d_in[2];
    const void* fq    = d_in[3];
    const int*  ei    = (const int*)d_in[4];
    const int*  ea    = (const int*)d_in[5];
    const void* Wmess = d_in[6];
    const void* bmess = d_in[7];
    const void* Wmatt = d_in[8];
    const void* bmatt = d_in[9];
    const void* maw   = d_in[10];
    const void* Wxatt = d_in[11];
    const void* bxatt = d_in[12];
    const void* xaw   = d_in[13];
    const void* gamma = d_in[14];
    const void* beta  = d_in[15];

    int*   flags  = (int*)d_ws;                           // 16
    int*   counts = flags + 16;                           // NN
    int*   offs   = counts + NN;                          // NN+1
    int*   cursor = offs + NN + 1;                        // NN
    int*   eids   = cursor + NN;                          // NE
    float* coeff  = (float*)(eids + NE);                  // NE
    float* rnorm  = coeff + NE;                           // NR*HID
    float* Rm     = rnorm + (size_t)NR * HID;             // NR*HID
    float* cmatt  = Rm + (size_t)NR * HID;                // HID
    float* cxatt  = cmatt + HID;                          // HID
    bf16*  Xmb    = (bf16*)(cxatt + HID);                 // NN*HID
    bf16*  smb    = Xmb + (size_t)NN * HID;               // NN*HID

    hipMemsetAsync(counts, 0, NN * sizeof(int), stream);

    detect_float<<<1, 64, 0, stream>>>((const unsigned int*)x,     NN * HID, flags + 0);
    detect_float<<<1, 64, 0, stream>>>((const unsigned int*)r,     NR * HID, flags + 1);
    detect_float<<<1, 64, 0, stream>>>((const unsigned int*)qc,    HID,      flags + 2);
    detect_float<<<1, 64, 0, stream>>>((const unsigned int*)fq,    HID,      flags + 3);
    detect_idx  <<<1, 64, 0, stream>>>(ei, flags + 4);
    detect_idx  <<<1, 64, 0, stream>>>(ea, flags + 5);
    detect_float<<<1, 64, 0, stream>>>((const unsigned int*)Wmess, 2 * HID * HID, flags + 6);
    detect_float<<<1, 64, 0, stream>>>((const unsigned int*)bmess, HID,      flags + 7);
    detect_float<<<1, 64, 0, stream>>>((const unsigned int*)Wmatt, 2 * HID * HID, flags + 8);
    detect_float<<<1, 64, 0, stream>>>((const unsigned int*)bmatt, HID,      flags + 9);
    detect_float<<<1, 64, 0, stream>>>((const unsigned int*)maw,   HID,      flags + 10);
    detect_float<<<1, 64, 0, stream>>>((const unsigned int*)Wxatt, 2 * HID * HID, flags + 11);
    detect_float<<<1, 64, 0, stream>>>((const unsigned int*)bxatt, HID,      flags + 12);
    detect_float<<<1, 64, 0, stream>>>((const unsigned int*)xaw,   HID,      flags + 13);
    detect_float<<<1, 64, 0, stream>>>((const unsigned int*)gamma, HID,      flags + 14);
    detect_float<<<1, 64, 0, stream>>>((const unsigned int*)beta,  HID,      flags + 15);

    bn_kernel<<<1, HID, 0, stream>>>(r, gamma, beta, flags, rnorm, d_out);
    precomp_kernel<<<1, HID, 0, stream>>>(Wmatt, bmatt, qc, Wxatt, bxatt, fq, flags,
                                          cmatt, cxatt);
    rm_kernel<<<NR, HID, 0, stream>>>(Wmess, bmess, flags, rnorm, Rm);
    xm_kernel<<<1024, HID, 0, stream>>>(x, Wmess, flags, Xmb);
    edge_coeff_kernel<<<1024, HID, 0, stream>>>(Xmb, Rm, Wmatt, cmatt, maw, ei, ea, flags,
                                                coeff);
    count_kernel<<<1024, 256, 0, stream>>>(ei, flags, counts);
    scan_kernel<<<1, 1024, 0, stream>>>(counts, offs);
    cursor_kernel<<<(NN + 255) / 256, 256, 0, stream>>>(offs, cursor);
    scatter_kernel<<<1024, 256, 0, stream>>>(ei, flags, cursor, eids);
    node_aggr_kernel<<<NN, HID, 0, stream>>>(Xmb, Rm, ei, ea, flags, offs, eids, coeff, smb);
    gate_kernel<<<1024, HID, 0, stream>>>(x, smb, Wxatt, cxatt, xaw, flags, d_out);
}

// Round 5
// 1107.543 us; speedup vs baseline: 1.6109x; 1.6109x over previous
//
#include <hip/hip_runtime.h>
#include <hip/hip_bf16.h>

#define HID 128
#define NN 50000
#define NR 500
#define NE 625000
#define LRELU 0.01f

typedef __hip_bfloat16 bf16;
typedef __attribute__((ext_vector_type(8))) short short8;
typedef __attribute__((ext_vector_type(4))) float float4_;

__device__ __forceinline__ float b2f(bf16 v) { return __bfloat162float(v); }
__device__ __forceinline__ bf16 f2b(float v) { return __float2bfloat16(v); }

__device__ __forceinline__ float san(float v) {
    return (v == v && v > -1e30f && v < 1e30f) ? v : 0.f;
}

__device__ __forceinline__ float ldf(const void* p, int i, int f32) {
    return f32 ? ((const float*)p)[i] : b2f(((const bf16*)p)[i]);
}
__device__ __forceinline__ void stf(void* p, int i, float v, int f32) {
    if (f32) ((float*)p)[i] = v;
    else ((bf16*)p)[i] = f2b(v);
}

__device__ __forceinline__ int clampi(int v, int hi) {
    return v < 0 ? 0 : (v >= hi ? hi - 1 : v);
}
__device__ __forceinline__ int idx_at(const int* p, int i, int is64) {
    return p[is64 ? (2 * i) : i];
}

__device__ __forceinline__ unsigned short bfbits(float v) {
    bf16 h = f2b(v);
    return *(unsigned short*)&h;
}
__device__ __forceinline__ unsigned int packbf2(float a, float b) {
    return (unsigned int)bfbits(a) | ((unsigned int)bfbits(b) << 16);
}
__device__ __forceinline__ float bflo(unsigned int u) { return __uint_as_float(u << 16); }
__device__ __forceinline__ float bfhi(unsigned int u) { return __uint_as_float(u & 0xffff0000u); }

__device__ __forceinline__ float xorReduce16(float v) {
    v += __shfl_xor(v, 1, 64);
    v += __shfl_xor(v, 2, 64);
    v += __shfl_xor(v, 4, 64);
    v += __shfl_xor(v, 8, 64);
    return v;
}

// ---------------------------------------------------------------- consolidated dtype detect
struct DetectArr {
    const void* p[16];
    int sz[16];
    int kind[16];  // 0 = float width vote, 1 = int64 odd-word test
};

__global__ void detect_all(DetectArr d, int* __restrict__ flags) {
    int b = blockIdx.x;
    if (d.kind[b] == 1) {
        if (threadIdx.x == 0) {
            const int* q = (const int*)d.p[b];
            int o = 0;
            for (int i = 0; i < 64; ++i) o |= q[2 * i + 1];
            flags[b] = (o == 0) ? 1 : 0;
        }
        return;
    }
    __shared__ int sb[64], sf[64];
    const unsigned int* w = (const unsigned int*)d.p[b];
    int K = d.sz[b] >> 1;
    if (K > 4096) K = 4096;
    int bv = 0, fv = 0;
    for (int i = threadIdx.x; i < K; i += 64) {
        unsigned int x = w[i];
        unsigned int lo = x & 0xFFFFu, hi = x >> 16;
        if (lo == 0u) {
            if (hi) fv++;
        } else {
            unsigned int e = (lo >> 7) & 0xFFu;
            if (e >= 90u && e <= 160u) bv++;
            else fv++;
        }
    }
    sb[threadIdx.x] = bv; sf[threadIdx.x] = fv;
    __syncthreads();
    if (threadIdx.x == 0) {
        int B = 0, F = 0;
        for (int i = 0; i < 64; ++i) { B += sb[i]; F += sf[i]; }
        flags[b] = (F > B) ? 1 : 0;
    }
}

// ---------------------------------------------------------------- BatchNorm over r (1024 thr)
__global__ void bn_kernel(const void* __restrict__ r, const void* __restrict__ gamma,
                          const void* __restrict__ beta, const int* __restrict__ flags,
                          float* __restrict__ rnorm, void* __restrict__ out_base) {
    __shared__ float sb[1024], sq[1024];
    __shared__ float muL[HID], scL[HID], beL[HID];
    const int fr = flags[1], fg = flags[14], fb = flags[15], fo = flags[0];
    int tid = threadIdx.x;
    int rr = tid >> 7, h = tid & 127;
    float s = 0.f, ss = 0.f;
    for (int i = rr; i < NR; i += 8) {
        float v = ldf(r, i * HID + h, fr);
        s += v; ss += v * v;
    }
    sb[tid] = s; sq[tid] = ss;
    __syncthreads();
    if (tid < HID) {
        float S = 0.f, SS = 0.f;
        for (int j = 0; j < 8; ++j) { S += sb[j * HID + tid]; SS += sq[j * HID + tid]; }
        float mu = S / NR;
        float var = SS / NR - mu * mu;
        if (var < 0.f) var = 0.f;
        muL[tid] = mu;
        scL[tid] = ldf(gamma, tid, fg) * rsqrtf(var + 1e-5f);
        beL[tid] = ldf(beta, tid, fb);
    }
    __syncthreads();
    float mu = muL[h], sc = scL[h], be = beL[h];
    for (int i = rr; i < NR; i += 8) {
        float v = san((ldf(r, i * HID + h, fr) - mu) * sc + be);
        rnorm[i * HID + h] = v;
        stf(out_base, NN * HID + i * HID + h, v, fo);
    }
}

// ---------------------------------------------------------------- edge-constant vectors
__global__ void precomp_kernel(const void* __restrict__ Wmatt, const void* __restrict__ bmatt,
                               const void* __restrict__ qc,
                               const void* __restrict__ Wxatt, const void* __restrict__ bxatt,
                               const void* __restrict__ fq, const int* __restrict__ flags,
                               float* __restrict__ cmatt, float* __restrict__ cxatt) {
    __shared__ float qcs[HID], fqs[HID];
    const int fWm = flags[8], fbm = flags[9], fqc = flags[2];
    const int fWx = flags[11], fbx = flags[12], ffq = flags[3];
    int h = threadIdx.x;
    qcs[h] = ldf(qc, h, fqc);
    fqs[h] = ldf(fq, h, ffq);
    __syncthreads();
    float a = ldf(bmatt, h, fbm), b = ldf(bxatt, h, fbx);
    for (int k = 0; k < HID; ++k) {
        a += ldf(Wmatt, h * 2 * HID + HID + k, fWm) * qcs[k];
        b += ldf(Wxatt, h * 2 * HID + HID + k, fWx) * fqs[k];
    }
    cmatt[h] = san(a);
    cxatt[h] = san(b);
}

// ---------------------------------------------------------------- Rmb[rel,h] (bf16)
__global__ void rm_kernel(const void* __restrict__ Wmess, const void* __restrict__ bmess,
                          const int* __restrict__ flags,
                          const float* __restrict__ rnorm, bf16* __restrict__ Rmb) {
    __shared__ float rl[HID];
    const int fW = flags[6], fb = flags[7];
    int rel = blockIdx.x, h = threadIdx.x;
    rl[h] = rnorm[rel * HID + h];
    __syncthreads();
    float acc = ldf(bmess, h, fb);
    for (int k = 0; k < HID; ++k)
        acc += ldf(Wmess, h * 2 * HID + HID + k, fW) * rl[k];
    Rmb[rel * HID + h] = f2b(san(acc));
}

// ================================================================ MFMA GEMM kernels
// Fragment layouts (mfma_f32_16x16x32_bf16):
//   A: lane l holds A[m=l&15][k=(l>>4)*8+j], j=0..7
//   B: lane l holds B[k=(l>>4)*8+j][n=l&15]
//   C/D: lane l, reg r holds D[row=(l>>4)*4+r][col=l&15]
#define MLDA 136  // LDS A-tile row stride in shorts (272 B: 16B-aligned, 2-way-free banks)

// ---------------------------------------------------------------- Xm = x @ Wmess[:, :128]^T (bf16 out)
__global__ __launch_bounds__(256) void xm_mfma(const void* __restrict__ x,
                                               const void* __restrict__ Wmess,
                                               const int* __restrict__ flags,
                                               bf16* __restrict__ Xmb) {
    __shared__ short ml[64 * MLDA];
    const int fx = flags[0], fW = flags[6];
    int tid = threadIdx.x;
    int l = tid & 63, w = tid >> 6;
    int quad = l >> 4, lo16 = l & 15;
    int nbase = w * 32;
    // preload B fragments: W[n][k], n = nbase + nt*16 + lo16, k = kk*32 + quad*8 + j
    short8 bfr[2][4];
#pragma unroll
    for (int nt = 0; nt < 2; ++nt) {
        int n = nbase + nt * 16 + lo16;
#pragma unroll
        for (int kk = 0; kk < 4; ++kk) {
            int k0 = kk * 32 + quad * 8;
            short8 b;
#pragma unroll
            for (int j = 0; j < 8; ++j)
                b[j] = (short)bfbits(ldf(Wmess, n * 2 * HID + k0 + j, fW));
            bfr[nt][kk] = b;
        }
    }
    // stage 64 node rows of x as bf16
    int tile = blockIdx.x;
#pragma unroll
    for (int p = 0; p < 8; ++p) {
        int rl_ = p * 8 + (tid >> 5);
        int node = clampi(tile * 64 + rl_, NN);
        int k4 = (tid & 31) * 4;
        float v0 = ldf(x, node * HID + k4, fx);
        float v1 = ldf(x, node * HID + k4 + 1, fx);
        float v2 = ldf(x, node * HID + k4 + 2, fx);
        float v3 = ldf(x, node * HID + k4 + 3, fx);
        unsigned int* dst = (unsigned int*)&ml[rl_ * MLDA + k4];
        dst[0] = packbf2(v0, v1);
        dst[1] = packbf2(v2, v3);
    }
    __syncthreads();
    float4_ acc[4][2];
#pragma unroll
    for (int mt = 0; mt < 4; ++mt)
#pragma unroll
        for (int nt = 0; nt < 2; ++nt)
            acc[mt][nt] = (float4_){0.f, 0.f, 0.f, 0.f};
#pragma unroll
    for (int kk = 0; kk < 4; ++kk) {
        short8 a[4];
#pragma unroll
        for (int mt = 0; mt < 4; ++mt)
            a[mt] = *(const short8*)&ml[(mt * 16 + lo16) * MLDA + kk * 32 + quad * 8];
#pragma unroll
        for (int mt = 0; mt < 4; ++mt)
#pragma unroll
            for (int nt = 0; nt < 2; ++nt)
                acc[mt][nt] = __builtin_amdgcn_mfma_f32_16x16x32_bf16(
                    a[mt], bfr[nt][kk], acc[mt][nt], 0, 0, 0);
    }
#pragma unroll
    for (int mt = 0; mt < 4; ++mt)
#pragma unroll
        for (int nt = 0; nt < 2; ++nt)
#pragma unroll
            for (int r = 0; r < 4; ++r) {
                int node = tile * 64 + mt * 16 + quad * 4 + r;
                if (node < NN)
                    Xmb[node * HID + nbase + nt * 16 + lo16] = f2b(san(acc[mt][nt][r]));
            }
}

// ---------------------------------------------------------------- edge logits (fused MFMA)
// coeff[e] = sum_h maw[h]*leaky( (Wmatt[:, :128] @ tanh(Xm[head]+Rm[rel]))_h + cmatt[h] )
__global__ __launch_bounds__(256) void edge_coeff_mfma(
        const bf16* __restrict__ Xmb, const bf16* __restrict__ Rmb,
        const void* __restrict__ Wmatt, const float* __restrict__ cmatt,
        const void* __restrict__ maw,
        const int* __restrict__ ei, const int* __restrict__ ea,
        const int* __restrict__ flags, float* __restrict__ coeff) {
    __shared__ short ml[64 * MLDA];
    __shared__ float swave[4][64];
    const int fWm = flags[8], fmw = flags[10];
    const int is64e = flags[4], is64a = flags[5];
    int tid = threadIdx.x;
    int l = tid & 63, w = tid >> 6;
    int quad = l >> 4, lo16 = l & 15;
    int nbase = w * 32;
    short8 bfr[2][4];
#pragma unroll
    for (int nt = 0; nt < 2; ++nt) {
        int n = nbase + nt * 16 + lo16;
#pragma unroll
        for (int kk = 0; kk < 4; ++kk) {
            int k0 = kk * 32 + quad * 8;
            short8 b;
#pragma unroll
            for (int j = 0; j < 8; ++j)
                b[j] = (short)bfbits(ldf(Wmatt, n * 2 * HID + k0 + j, fWm));
            bfr[nt][kk] = b;
        }
    }
    int n0 = nbase + lo16, n1 = n0 + 16;
    float c0 = cmatt[n0], c1 = cmatt[n1];
    float w0 = ldf(maw, n0, fmw), w1 = ldf(maw, n1, fmw);

    int tile = blockIdx.x;
    // stage mess = tanh(Xm[head]+Rm[rel]) for 64 edges
#pragma unroll
    for (int p = 0; p < 8; ++p) {
        int el = p * 8 + (tid >> 5);
        int e = tile * 64 + el;
        int ec = e < NE ? e : NE - 1;
        int head = clampi(idx_at(ei, ec, is64e), NN);
        int rel = clampi(idx_at(ea, ec, is64a), NR);
        int k4 = (tid & 31) * 4;
        uint2 xv = *(const uint2*)&Xmb[head * HID + k4];
        uint2 rv = *(const uint2*)&Rmb[rel * HID + k4];
        float t0 = tanhf(bflo(xv.x) + bflo(rv.x));
        float t1 = tanhf(bfhi(xv.x) + bfhi(rv.x));
        float t2 = tanhf(bflo(xv.y) + bflo(rv.y));
        float t3 = tanhf(bfhi(xv.y) + bfhi(rv.y));
        unsigned int* dst = (unsigned int*)&ml[el * MLDA + k4];
        dst[0] = packbf2(t0, t1);
        dst[1] = packbf2(t2, t3);
    }
    __syncthreads();
    float4_ acc[4][2];
#pragma unroll
    for (int mt = 0; mt < 4; ++mt)
#pragma unroll
        for (int nt = 0; nt < 2; ++nt)
            acc[mt][nt] = (float4_){0.f, 0.f, 0.f, 0.f};
#pragma unroll
    for (int kk = 0; kk < 4; ++kk) {
        short8 a[4];
#pragma unroll
        for (int mt = 0; mt < 4; ++mt)
            a[mt] = *(const short8*)&ml[(mt * 16 + lo16) * MLDA + kk * 32 + quad * 8];
#pragma unroll
        for (int mt = 0; mt < 4; ++mt)
#pragma unroll
            for (int nt = 0; nt < 2; ++nt)
                acc[mt][nt] = __builtin_amdgcn_mfma_f32_16x16x32_bf16(
                    a[mt], bfr[nt][kk], acc[mt][nt], 0, 0, 0);
    }
    // epilogue: leaky + weighted h-reduction
#pragma unroll
    for (int mt = 0; mt < 4; ++mt)
#pragma unroll
        for (int r = 0; r < 4; ++r) {
            float z0 = acc[mt][0][r] + c0;
            z0 = z0 > 0.f ? z0 : LRELU * z0;
            float z1 = acc[mt][1][r] + c1;
            z1 = z1 > 0.f ? z1 : LRELU * z1;
            float s = w0 * z0 + w1 * z1;
            s = xorReduce16(s);
            if (lo16 == 0) swave[w][mt * 16 + quad * 4 + r] = s;
        }
    __syncthreads();
    if (tid < 64) {
        int e = tile * 64 + tid;
        if (e < NE)
            coeff[e] = san(swave[0][tid] + swave[1][tid] + swave[2][tid] + swave[3][tid]);
    }
}

// ---------------------------------------------------------------- gate (fused MFMA + softmax combine)
__global__ __launch_bounds__(256) void gate_mfma(
        const void* __restrict__ x, const bf16* __restrict__ smb,
        const void* __restrict__ Wxatt, const float* __restrict__ cxatt,
        const void* __restrict__ xaw, const int* __restrict__ flags,
        void* __restrict__ outx) {
    __shared__ short ml[64 * MLDA];
    __shared__ float swave[4][64];
    __shared__ float lgL[64];
    const int fx = flags[0], fWx = flags[11], fxw = flags[13], fo = flags[0];
    int tid = threadIdx.x;
    int l = tid & 63, w = tid >> 6;
    int quad = l >> 4, lo16 = l & 15;
    int nbase = w * 32;
    short8 bfr[2][4];
#pragma unroll
    for (int nt = 0; nt < 2; ++nt) {
        int n = nbase + nt * 16 + lo16;
#pragma unroll
        for (int kk = 0; kk < 4; ++kk) {
            int k0 = kk * 32 + quad * 8;
            short8 b;
#pragma unroll
            for (int j = 0; j < 8; ++j)
                b[j] = (short)bfbits(ldf(Wxatt, n * 2 * HID + k0 + j, fWx));
            bfr[nt][kk] = b;
        }
    }
    int n0 = nbase + lo16, n1 = n0 + 16;
    float c0 = cxatt[n0], c1 = cxatt[n1];
    float w0 = ldf(xaw, n0, fxw), w1 = ldf(xaw, n1, fxw);

    int tile = blockIdx.x;
    // rows: 2j = x[node], 2j+1 = sum_mess[node], 32 nodes per tile
#pragma unroll
    for (int p = 0; p < 8; ++p) {
        int rl_ = p * 8 + (tid >> 5);
        int node = clampi(tile * 32 + (rl_ >> 1), NN);
        int k4 = (tid & 31) * 4;
        float v0, v1, v2, v3;
        if (rl_ & 1) {
            v0 = b2f(smb[node * HID + k4]);
            v1 = b2f(smb[node * HID + k4 + 1]);
            v2 = b2f(smb[node * HID + k4 + 2]);
            v3 = b2f(smb[node * HID + k4 + 3]);
        } else {
            v0 = ldf(x, node * HID + k4, fx);
            v1 = ldf(x, node * HID + k4 + 1, fx);
            v2 = ldf(x, node * HID + k4 + 2, fx);
            v3 = ldf(x, node * HID + k4 + 3, fx);
        }
        unsigned int* dst = (unsigned int*)&ml[rl_ * MLDA + k4];
        dst[0] = packbf2(v0, v1);
        dst[1] = packbf2(v2, v3);
    }
    __syncthreads();
    float4_ acc[4][2];
#pragma unroll
    for (int mt = 0; mt < 4; ++mt)
#pragma unroll
        for (int nt = 0; nt < 2; ++nt)
            acc[mt][nt] = (float4_){0.f, 0.f, 0.f, 0.f};
#pragma unroll
    for (int kk = 0; kk < 4; ++kk) {
        short8 a[4];
#pragma unroll
        for (int mt = 0; mt < 4; ++mt)
            a[mt] = *(const short8*)&ml[(mt * 16 + lo16) * MLDA + kk * 32 + quad * 8];
#pragma unroll
        for (int mt = 0; mt < 4; ++mt)
#pragma unroll
            for (int nt = 0; nt < 2; ++nt)
                acc[mt][nt] = __builtin_amdgcn_mfma_f32_16x16x32_bf16(
                    a[mt], bfr[nt][kk], acc[mt][nt], 0, 0, 0);
    }
#pragma unroll
    for (int mt = 0; mt < 4; ++mt)
#pragma unroll
        for (int r = 0; r < 4; ++r) {
            float z0 = acc[mt][0][r] + c0;
            z0 = z0 > 0.f ? z0 : LRELU * z0;
            float z1 = acc[mt][1][r] + c1;
            z1 = z1 > 0.f ? z1 : LRELU * z1;
            float s = w0 * z0 + w1 * z1;
            s = xorReduce16(s);
            if (lo16 == 0) swave[w][mt * 16 + quad * 4 + r] = s;
        }
    __syncthreads();
    if (tid < 64)
        lgL[tid] = san(swave[0][tid] + swave[1][tid] + swave[2][tid] + swave[3][tid]);
    __syncthreads();
    // output: out[n,h] = softmax(lg[2n],lg[2n+1]) · (x[n,h], sm[n,h])
#pragma unroll
    for (int it = 0; it < 16; ++it) {
        int idx = tid + 256 * it;       // 0..4095
        int nl = idx >> 7, h = idx & 127;
        int node = tile * 32 + nl;
        if (node < NN) {
            float g0 = lgL[2 * nl], g1 = lgL[2 * nl + 1];
            float mm = fmaxf(g0, g1);
            float e0 = expf(g0 - mm), e1 = expf(g1 - mm);
            float inv = 1.f / (e0 + e1);
            float xv = ldf(x, node * HID + h, fx);
            float sv = b2f(smb[node * HID + h]);
            stf(outx, node * HID + h, san((e0 * xv + e1 * sv) * inv), fo);
        }
    }
}

// ---------------------------------------------------------------- CSR build
__global__ void count_kernel(const int* __restrict__ ei, const int* __restrict__ flags,
                             int* __restrict__ counts) {
    const int is64e = flags[4];
    for (int e = blockIdx.x * blockDim.x + threadIdx.x; e < NE; e += gridDim.x * blockDim.x) {
        int tail = clampi(idx_at(ei, NE + e, is64e), NN);
        atomicAdd(&counts[tail], 1);
    }
}

// chunked scan: 1024 threads, ~49 elements each, 1 log-step block scan
__global__ void scan_kernel(const int* __restrict__ counts, int* __restrict__ offs,
                            int* __restrict__ cursor) {
    __shared__ int buf[1024];
    int t = threadIdx.x;
    const int C = (NN + 1023) / 1024;
    int lo = t * C, hi = lo + C;
    if (lo > NN) lo = NN;
    if (hi > NN) hi = NN;
    int tot = 0;
    for (int i = lo; i < hi; ++i) tot += counts[i];
    buf[t] = tot;
    __syncthreads();
    for (int off = 1; off < 1024; off <<= 1) {
        int add = (t >= off) ? buf[t - off] : 0;
        __syncthreads();
        buf[t] += add;
        __syncthreads();
    }
    int base = buf[t] - tot;  // exclusive prefix of this chunk
    int run = 0;
    for (int i = lo; i < hi; ++i) {
        int v = base + run;
        offs[i] = v;
        cursor[i] = v;
        run += counts[i];
    }
    if (t == 1023) offs[NN] = buf[1023];
}

__global__ void scatter_kernel(const int* __restrict__ ei, const int* __restrict__ flags,
                               int* __restrict__ cursor, int* __restrict__ eids) {
    const int is64e = flags[4];
    for (int e = blockIdx.x * blockDim.x + threadIdx.x; e < NE; e += gridDim.x * blockDim.x) {
        int tail = clampi(idx_at(ei, NE + e, is64e), NN);
        int pos = atomicAdd(&cursor[tail], 1);
        if (pos >= 0 && pos < NE) eids[pos] = e;
    }
}

// ---------------------------------------------------------------- per-node softmax + aggregation
__global__ void node_aggr_kernel(const bf16* __restrict__ Xmb, const bf16* __restrict__ Rmb,
                                 const int* __restrict__ ei, const int* __restrict__ ea,
                                 const int* __restrict__ flags,
                                 const int* __restrict__ offs, const int* __restrict__ eids,
                                 const float* __restrict__ coeff, bf16* __restrict__ smb) {
    int n = blockIdx.x;
    int h = threadIdx.x;
    int s = offs[n], en = offs[n + 1];
    const int is64e = flags[4], is64a = flags[5];
    float m = -INFINITY;
    for (int i = s; i < en; ++i) m = fmaxf(m, coeff[eids[i]]);
    float l = 0.f;
    for (int i = s; i < en; ++i) l += expf(coeff[eids[i]] - m);
    float inv = 1.f / (l + 1e-16f);
    float acc = 0.f;
    for (int i = s; i < en; ++i) {
        int e = eids[i];
        int head = clampi(idx_at(ei, e, is64e), NN);
        int rel = clampi(idx_at(ea, e, is64a), NR);
        float w = expf(coeff[e] - m) * inv;
        acc += w * tanhf(b2f(Xmb[head * HID + h]) + b2f(Rmb[rel * HID + h]));
    }
    smb[n * HID + h] = f2b(san(acc));
}

extern "C" void kernel_launch(void* const* d_in, const int* in_sizes, int n_in,
                              void* d_out, int out_size, void* d_ws, size_t ws_size,
                              hipStream_t stream) {
    const void* x     = d_in[0];
    const void* r     = d_in[1];
    const void* qc    = d_in[2];
    const void* fq    = d_in[3];
    const int*  ei    = (const int*)d_in[4];
    const int*  ea    = (const int*)d_in[5];
    const void* Wmess = d_in[6];
    const void* bmess = d_in[7];
    const void* Wmatt = d_in[8];
    const void* bmatt = d_in[9];
    const void* maw   = d_in[10];
    const void* Wxatt = d_in[11];
    const void* bxatt = d_in[12];
    const void* xaw   = d_in[13];
    const void* gamma = d_in[14];
    const void* beta  = d_in[15];

    // ws layout (~31.6 MB), 16B-aligned sections
    int*   flags  = (int*)d_ws;                        // 16
    int*   counts = flags + 16;                        // NN
    int*   offs   = counts + NN;                       // NN+1
    int*   cursor = offs + NN + 1;                     // NN, then pad 3
    int*   eids   = cursor + NN + 3;                   // NE  (base 16B-aligned)
    float* coeff  = (float*)(eids + NE);               // NE
    float* rnorm  = coeff + NE;                        // NR*HID
    float* cmatt  = rnorm + (size_t)NR * HID;          // HID
    float* cxatt  = cmatt + HID;                       // HID
    bf16*  Rmb    = (bf16*)(cxatt + HID);              // NR*HID
    bf16*  Xmb    = Rmb + (size_t)NR * HID;            // NN*HID
    bf16*  smb    = Xmb + (size_t)NN * HID;            // NN*HID

    hipMemsetAsync(counts, 0, NN * sizeof(int), stream);

    DetectArr da;
    const void* ps[16] = {x, r, qc, fq, ei, ea, Wmess, bmess, Wmatt, bmatt, maw,
                          Wxatt, bxatt, xaw, gamma, beta};
    int szs[16] = {NN * HID, NR * HID, HID, HID, 2 * NE, NE, 2 * HID * HID, HID,
                   2 * HID * HID, HID, HID, 2 * HID * HID, HID, HID, HID, HID};
    for (int i = 0; i < 16; ++i) {
        da.p[i] = ps[i];
        da.sz[i] = szs[i];
        da.kind[i] = (i == 4 || i == 5) ? 1 : 0;
    }
    detect_all<<<16, 64, 0, stream>>>(da, flags);

    bn_kernel<<<1, 1024, 0, stream>>>(r, gamma, beta, flags, rnorm, d_out);
    precomp_kernel<<<1, HID, 0, stream>>>(Wmatt, bmatt, qc, Wxatt, bxatt, fq, flags,
                                          cmatt, cxatt);
    rm_kernel<<<NR, HID, 0, stream>>>(Wmess, bmess, flags, rnorm, Rmb);
    xm_mfma<<<(NN + 63) / 64, 256, 0, stream>>>(x, Wmess, flags, Xmb);
    edge_coeff_mfma<<<(NE + 63) / 64, 256, 0, stream>>>(Xmb, Rmb, Wmatt, cmatt, maw,
                                                        ei, ea, flags, coeff);
    count_kernel<<<1024, 256, 0, stream>>>(ei, flags, counts);
    scan_kernel<<<1, 1024, 0, stream>>>(counts, offs, cursor);
    scatter_kernel<<<1024, 256, 0, stream>>>(ei, flags, cursor, eids);
    node_aggr_kernel<<<NN, HID, 0, stream>>>(Xmb, Rmb, ei, ea, flags, offs, eids, coeff,
                                             smb);
    gate_mfma<<<(NN + 31) / 32, 256, 0, stream>>>(x, smb, Wxatt, cxatt, xaw, flags, d_out);
}

// Round 6
// 741.976 us; speedup vs baseline: 2.4046x; 1.4927x over previous
//
#include <hip/hip_runtime.h>
#include <hip/hip_bf16.h>

#define HID 128
#define NN 50000
#define NR 500
#define NE 625000
#define LRELU 0.01f

typedef __hip_bfloat16 bf16;
typedef __attribute__((ext_vector_type(8))) short short8;
typedef __attribute__((ext_vector_type(4))) float float4_;

__device__ __forceinline__ float b2f(bf16 v) { return __bfloat162float(v); }
__device__ __forceinline__ bf16 f2b(float v) { return __float2bfloat16(v); }

__device__ __forceinline__ float san(float v) {
    return (v == v && v > -1e30f && v < 1e30f) ? v : 0.f;
}

__device__ __forceinline__ float ldf(const void* p, int i, int f32) {
    return f32 ? ((const float*)p)[i] : b2f(((const bf16*)p)[i]);
}
__device__ __forceinline__ void stf(void* p, int i, float v, int f32) {
    if (f32) ((float*)p)[i] = v;
    else ((bf16*)p)[i] = f2b(v);
}

__device__ __forceinline__ int clampi(int v, int hi) {
    return v < 0 ? 0 : (v >= hi ? hi - 1 : v);
}
__device__ __forceinline__ int idx_at(const int* p, int i, int is64) {
    return p[is64 ? (2 * i) : i];
}

__device__ __forceinline__ unsigned short bfbits(float v) {
    bf16 h = f2b(v);
    return *(unsigned short*)&h;
}
__device__ __forceinline__ unsigned int packbf2(float a, float b) {
    return (unsigned int)bfbits(a) | ((unsigned int)bfbits(b) << 16);
}
__device__ __forceinline__ float bflo(unsigned int u) { return __uint_as_float(u << 16); }
__device__ __forceinline__ float bfhi(unsigned int u) { return __uint_as_float(u & 0xffff0000u); }

__device__ __forceinline__ float xorReduce16(float v) {
    v += __shfl_xor(v, 1, 64);
    v += __shfl_xor(v, 2, 64);
    v += __shfl_xor(v, 4, 64);
    v += __shfl_xor(v, 8, 64);
    return v;
}
__device__ __forceinline__ float waveMax(float v) {
#pragma unroll
    for (int o = 1; o < 64; o <<= 1) v = fmaxf(v, __shfl_xor(v, o, 64));
    return v;
}
__device__ __forceinline__ float waveSum(float v) {
#pragma unroll
    for (int o = 1; o < 64; o <<= 1) v += __shfl_xor(v, o, 64);
    return v;
}

// ---------------------------------------------------------------- consolidated dtype detect
struct DetectArr {
    const void* p[16];
    int sz[16];
    int kind[16];  // 0 = float width vote, 1 = int64 odd-word test
};

__global__ void detect_all(DetectArr d, int* __restrict__ flags) {
    int b = blockIdx.x;
    if (d.kind[b] == 1) {
        if (threadIdx.x == 0) {
            const int* q = (const int*)d.p[b];
            int o = 0;
            for (int i = 0; i < 64; ++i) o |= q[2 * i + 1];
            flags[b] = (o == 0) ? 1 : 0;
        }
        return;
    }
    __shared__ int sb[64], sf[64];
    const unsigned int* w = (const unsigned int*)d.p[b];
    int K = d.sz[b] >> 1;
    if (K > 4096) K = 4096;
    int bv = 0, fv = 0;
    for (int i = threadIdx.x; i < K; i += 64) {
        unsigned int x = w[i];
        unsigned int lo = x & 0xFFFFu, hi = x >> 16;
        if (lo == 0u) {
            if (hi) fv++;
        } else {
            unsigned int e = (lo >> 7) & 0xFFu;
            if (e >= 90u && e <= 160u) bv++;
            else fv++;
        }
    }
    sb[threadIdx.x] = bv; sf[threadIdx.x] = fv;
    __syncthreads();
    if (threadIdx.x == 0) {
        int B = 0, F = 0;
        for (int i = 0; i < 64; ++i) { B += sb[i]; F += sf[i]; }
        flags[b] = (F > B) ? 1 : 0;
    }
}

// ---------------------------------------------------------------- BatchNorm over r
__global__ void bn_kernel(const void* __restrict__ r, const void* __restrict__ gamma,
                          const void* __restrict__ beta, const int* __restrict__ flags,
                          float* __restrict__ rnorm, void* __restrict__ out_base) {
    __shared__ float sb[1024], sq[1024];
    __shared__ float muL[HID], scL[HID], beL[HID];
    const int fr = flags[1], fg = flags[14], fb = flags[15], fo = flags[0];
    int tid = threadIdx.x;
    int rr = tid >> 7, h = tid & 127;
    float s = 0.f, ss = 0.f;
    for (int i = rr; i < NR; i += 8) {
        float v = ldf(r, i * HID + h, fr);
        s += v; ss += v * v;
    }
    sb[tid] = s; sq[tid] = ss;
    __syncthreads();
    if (tid < HID) {
        float S = 0.f, SS = 0.f;
        for (int j = 0; j < 8; ++j) { S += sb[j * HID + tid]; SS += sq[j * HID + tid]; }
        float mu = S / NR;
        float var = SS / NR - mu * mu;
        if (var < 0.f) var = 0.f;
        muL[tid] = mu;
        scL[tid] = ldf(gamma, tid, fg) * rsqrtf(var + 1e-5f);
        beL[tid] = ldf(beta, tid, fb);
    }
    __syncthreads();
    float mu = muL[h], sc = scL[h], be = beL[h];
    for (int i = rr; i < NR; i += 8) {
        float v = san((ldf(r, i * HID + h, fr) - mu) * sc + be);
        rnorm[i * HID + h] = v;
        stf(out_base, NN * HID + i * HID + h, v, fo);
    }
}

// ---------------------------------------------------------------- edge-constant vectors
__global__ void precomp_kernel(const void* __restrict__ Wmatt, const void* __restrict__ bmatt,
                               const void* __restrict__ qc,
                               const void* __restrict__ Wxatt, const void* __restrict__ bxatt,
                               const void* __restrict__ fq, const int* __restrict__ flags,
                               float* __restrict__ cmatt, float* __restrict__ cxatt) {
    __shared__ float qcs[HID], fqs[HID];
    const int fWm = flags[8], fbm = flags[9], fqc = flags[2];
    const int fWx = flags[11], fbx = flags[12], ffq = flags[3];
    int h = threadIdx.x;
    qcs[h] = ldf(qc, h, fqc);
    fqs[h] = ldf(fq, h, ffq);
    __syncthreads();
    float a = ldf(bmatt, h, fbm), b = ldf(bxatt, h, fbx);
    for (int k = 0; k < HID; ++k) {
        a += ldf(Wmatt, h * 2 * HID + HID + k, fWm) * qcs[k];
        b += ldf(Wxatt, h * 2 * HID + HID + k, fWx) * fqs[k];
    }
    cmatt[h] = san(a);
    cxatt[h] = san(b);
}

// ---------------------------------------------------------------- Rmb[rel,h] (bf16)
__global__ void rm_kernel(const void* __restrict__ Wmess, const void* __restrict__ bmess,
                          const int* __restrict__ flags,
                          const float* __restrict__ rnorm, bf16* __restrict__ Rmb) {
    __shared__ float rl[HID];
    const int fW = flags[6], fb = flags[7];
    int rel = blockIdx.x, h = threadIdx.x;
    rl[h] = rnorm[rel * HID + h];
    __syncthreads();
    float acc = f2b(0.f), a = ldf(bmess, h, fb);
    (void)acc;
    for (int k = 0; k < HID; ++k)
        a += ldf(Wmess, h * 2 * HID + HID + k, fW) * rl[k];
    Rmb[rel * HID + h] = f2b(san(a));
}

// ================================================================ MFMA kernels
// Fragment layouts (mfma_f32_16x16x32_bf16):
//   A: lane l holds A[m=l&15][k=(l>>4)*8+j]; B: lane l holds B[k=(l>>4)*8+j][n=l&15]
//   C/D: lane l, reg r holds D[row=(l>>4)*4+r][col=l&15]
#define MLDA 136

// ---------------------------------------------------------------- Xm = x @ Wmess[:, :128]^T (persistent)
__global__ __launch_bounds__(256, 4) void xm_mfma(const void* __restrict__ x,
                                                  const void* __restrict__ Wmess,
                                                  const int* __restrict__ flags,
                                                  bf16* __restrict__ Xmb) {
    __shared__ short ml[64 * MLDA];
    const int fx = flags[0], fW = flags[6];
    int tid = threadIdx.x;
    int l = tid & 63, w = tid >> 6;
    int quad = l >> 4, lo16 = l & 15;
    int nbase = w * 32;
    short8 bfr[2][4];
#pragma unroll
    for (int nt = 0; nt < 2; ++nt) {
        int n = nbase + nt * 16 + lo16;
#pragma unroll
        for (int kk = 0; kk < 4; ++kk) {
            int k0 = kk * 32 + quad * 8;
            short8 b;
#pragma unroll
            for (int j = 0; j < 8; ++j)
                b[j] = (short)bfbits(ldf(Wmess, n * 2 * HID + k0 + j, fW));
            bfr[nt][kk] = b;
        }
    }
    const int ntiles = (NN + 63) / 64;
    for (int tile = blockIdx.x; tile < ntiles; tile += gridDim.x) {
        __syncthreads();
#pragma unroll
        for (int p = 0; p < 8; ++p) {
            int rl_ = p * 8 + (tid >> 5);
            int node = clampi(tile * 64 + rl_, NN);
            int k4 = (tid & 31) * 4;
            float v0 = ldf(x, node * HID + k4, fx);
            float v1 = ldf(x, node * HID + k4 + 1, fx);
            float v2 = ldf(x, node * HID + k4 + 2, fx);
            float v3 = ldf(x, node * HID + k4 + 3, fx);
            unsigned int* dst = (unsigned int*)&ml[rl_ * MLDA + k4];
            dst[0] = packbf2(v0, v1);
            dst[1] = packbf2(v2, v3);
        }
        __syncthreads();
        float4_ acc[4][2];
#pragma unroll
        for (int mt = 0; mt < 4; ++mt)
#pragma unroll
            for (int nt = 0; nt < 2; ++nt)
                acc[mt][nt] = (float4_){0.f, 0.f, 0.f, 0.f};
#pragma unroll
        for (int kk = 0; kk < 4; ++kk) {
            short8 a[4];
#pragma unroll
            for (int mt = 0; mt < 4; ++mt)
                a[mt] = *(const short8*)&ml[(mt * 16 + lo16) * MLDA + kk * 32 + quad * 8];
#pragma unroll
            for (int mt = 0; mt < 4; ++mt)
#pragma unroll
                for (int nt = 0; nt < 2; ++nt)
                    acc[mt][nt] = __builtin_amdgcn_mfma_f32_16x16x32_bf16(
                        a[mt], bfr[nt][kk], acc[mt][nt], 0, 0, 0);
        }
#pragma unroll
        for (int mt = 0; mt < 4; ++mt)
#pragma unroll
            for (int nt = 0; nt < 2; ++nt)
#pragma unroll
                for (int r = 0; r < 4; ++r) {
                    int node = tile * 64 + mt * 16 + quad * 4 + r;
                    if (node < NN)
                        Xmb[node * HID + nbase + nt * 16 + lo16] = f2b(san(acc[mt][nt][r]));
                }
    }
}

// ---------------------------------------------------------------- edge logits (persistent + prefetch, CSR-ordered out)
__global__ __launch_bounds__(256, 4) void edge_coeff_mfma(
        const bf16* __restrict__ Xmb, const bf16* __restrict__ Rmb,
        const void* __restrict__ Wmatt, const float* __restrict__ cmatt,
        const void* __restrict__ maw,
        const int* __restrict__ ei, const int* __restrict__ ea,
        const int* __restrict__ flags, const int* __restrict__ pos,
        float* __restrict__ ccsr) {
    __shared__ short ml[64 * MLDA];
    __shared__ float swave[4][64];
    const int fWm = flags[8], fmw = flags[10];
    const int is64e = flags[4], is64a = flags[5];
    int tid = threadIdx.x;
    int l = tid & 63, w = tid >> 6;
    int quad = l >> 4, lo16 = l & 15;
    int nbase = w * 32;
    short8 bfr[2][4];
#pragma unroll
    for (int nt = 0; nt < 2; ++nt) {
        int n = nbase + nt * 16 + lo16;
#pragma unroll
        for (int kk = 0; kk < 4; ++kk) {
            int k0 = kk * 32 + quad * 8;
            short8 b;
#pragma unroll
            for (int j = 0; j < 8; ++j)
                b[j] = (short)bfbits(ldf(Wmatt, n * 2 * HID + k0 + j, fWm));
            bfr[nt][kk] = b;
        }
    }
    int n0 = nbase + lo16, n1 = n0 + 16;
    float c0 = cmatt[n0], c1 = cmatt[n1];
    float w0 = ldf(maw, n0, fmw), w1 = ldf(maw, n1, fmw);

    const int ntiles = (NE + 63) / 64;
    const int k4 = (tid & 31) * 4;
    const int elrow = tid >> 5;
    uint2 px[8], pr[8];

    // prefetch first tile
    int T = blockIdx.x;
    if (T < ntiles) {
#pragma unroll
        for (int p = 0; p < 8; ++p) {
            int e = T * 64 + p * 8 + elrow;
            int ec = e < NE ? e : NE - 1;
            int head = clampi(idx_at(ei, ec, is64e), NN);
            int rel = clampi(idx_at(ea, ec, is64a), NR);
            px[p] = *(const uint2*)&Xmb[head * HID + k4];
            pr[p] = *(const uint2*)&Rmb[rel * HID + k4];
        }
    }
    for (; T < ntiles; T += gridDim.x) {
        __syncthreads();
#pragma unroll
        for (int p = 0; p < 8; ++p) {
            int el = p * 8 + elrow;
            float t0 = tanhf(bflo(px[p].x) + bflo(pr[p].x));
            float t1 = tanhf(bfhi(px[p].x) + bfhi(pr[p].x));
            float t2 = tanhf(bflo(px[p].y) + bflo(pr[p].y));
            float t3 = tanhf(bfhi(px[p].y) + bfhi(pr[p].y));
            unsigned int* dst = (unsigned int*)&ml[el * MLDA + k4];
            dst[0] = packbf2(t0, t1);
            dst[1] = packbf2(t2, t3);
        }
        __syncthreads();
        // prefetch next tile while MFMAs run
        int Tn = T + gridDim.x;
        if (Tn < ntiles) {
#pragma unroll
            for (int p = 0; p < 8; ++p) {
                int e = Tn * 64 + p * 8 + elrow;
                int ec = e < NE ? e : NE - 1;
                int head = clampi(idx_at(ei, ec, is64e), NN);
                int rel = clampi(idx_at(ea, ec, is64a), NR);
                px[p] = *(const uint2*)&Xmb[head * HID + k4];
                pr[p] = *(const uint2*)&Rmb[rel * HID + k4];
            }
        }
        float4_ acc[4][2];
#pragma unroll
        for (int mt = 0; mt < 4; ++mt)
#pragma unroll
            for (int nt = 0; nt < 2; ++nt)
                acc[mt][nt] = (float4_){0.f, 0.f, 0.f, 0.f};
#pragma unroll
        for (int kk = 0; kk < 4; ++kk) {
            short8 a[4];
#pragma unroll
            for (int mt = 0; mt < 4; ++mt)
                a[mt] = *(const short8*)&ml[(mt * 16 + lo16) * MLDA + kk * 32 + quad * 8];
#pragma unroll
            for (int mt = 0; mt < 4; ++mt)
#pragma unroll
                for (int nt = 0; nt < 2; ++nt)
                    acc[mt][nt] = __builtin_amdgcn_mfma_f32_16x16x32_bf16(
                        a[mt], bfr[nt][kk], acc[mt][nt], 0, 0, 0);
        }
#pragma unroll
        for (int mt = 0; mt < 4; ++mt)
#pragma unroll
            for (int r = 0; r < 4; ++r) {
                float z0 = acc[mt][0][r] + c0;
                z0 = z0 > 0.f ? z0 : LRELU * z0;
                float z1 = acc[mt][1][r] + c1;
                z1 = z1 > 0.f ? z1 : LRELU * z1;
                float s = w0 * z0 + w1 * z1;
                s = xorReduce16(s);
                if (lo16 == 0) swave[w][mt * 16 + quad * 4 + r] = s;
            }
        __syncthreads();
        if (tid < 64) {
            int e = T * 64 + tid;
            if (e < NE) {
                float v = san(swave[0][tid] + swave[1][tid] + swave[2][tid] + swave[3][tid]);
                ccsr[pos[e]] = v;
            }
        }
    }
}

// ---------------------------------------------------------------- gate (persistent)
__global__ __launch_bounds__(256, 4) void gate_mfma(
        const void* __restrict__ x, const bf16* __restrict__ smb,
        const void* __restrict__ Wxatt, const float* __restrict__ cxatt,
        const void* __restrict__ xaw, const int* __restrict__ flags,
        void* __restrict__ outx) {
    __shared__ short ml[64 * MLDA];
    __shared__ float swave[4][64];
    __shared__ float lgL[64];
    const int fx = flags[0], fWx = flags[11], fxw = flags[13], fo = flags[0];
    int tid = threadIdx.x;
    int l = tid & 63, w = tid >> 6;
    int quad = l >> 4, lo16 = l & 15;
    int nbase = w * 32;
    short8 bfr[2][4];
#pragma unroll
    for (int nt = 0; nt < 2; ++nt) {
        int n = nbase + nt * 16 + lo16;
#pragma unroll
        for (int kk = 0; kk < 4; ++kk) {
            int k0 = kk * 32 + quad * 8;
            short8 b;
#pragma unroll
            for (int j = 0; j < 8; ++j)
                b[j] = (short)bfbits(ldf(Wxatt, n * 2 * HID + k0 + j, fWx));
            bfr[nt][kk] = b;
        }
    }
    int n0 = nbase + lo16, n1 = n0 + 16;
    float c0 = cxatt[n0], c1 = cxatt[n1];
    float w0 = ldf(xaw, n0, fxw), w1 = ldf(xaw, n1, fxw);

    const int ntiles = (NN + 31) / 32;
    for (int tile = blockIdx.x; tile < ntiles; tile += gridDim.x) {
        __syncthreads();
#pragma unroll
        for (int p = 0; p < 8; ++p) {
            int rl_ = p * 8 + (tid >> 5);
            int node = clampi(tile * 32 + (rl_ >> 1), NN);
            int k4 = (tid & 31) * 4;
            float v0, v1, v2, v3;
            if (rl_ & 1) {
                v0 = b2f(smb[node * HID + k4]);
                v1 = b2f(smb[node * HID + k4 + 1]);
                v2 = b2f(smb[node * HID + k4 + 2]);
                v3 = b2f(smb[node * HID + k4 + 3]);
            } else {
                v0 = ldf(x, node * HID + k4, fx);
                v1 = ldf(x, node * HID + k4 + 1, fx);
                v2 = ldf(x, node * HID + k4 + 2, fx);
                v3 = ldf(x, node * HID + k4 + 3, fx);
            }
            unsigned int* dst = (unsigned int*)&ml[rl_ * MLDA + k4];
            dst[0] = packbf2(v0, v1);
            dst[1] = packbf2(v2, v3);
        }
        __syncthreads();
        float4_ acc[4][2];
#pragma unroll
        for (int mt = 0; mt < 4; ++mt)
#pragma unroll
            for (int nt = 0; nt < 2; ++nt)
                acc[mt][nt] = (float4_){0.f, 0.f, 0.f, 0.f};
#pragma unroll
        for (int kk = 0; kk < 4; ++kk) {
            short8 a[4];
#pragma unroll
            for (int mt = 0; mt < 4; ++mt)
                a[mt] = *(const short8*)&ml[(mt * 16 + lo16) * MLDA + kk * 32 + quad * 8];
#pragma unroll
            for (int mt = 0; mt < 4; ++mt)
#pragma unroll
                for (int nt = 0; nt < 2; ++nt)
                    acc[mt][nt] = __builtin_amdgcn_mfma_f32_16x16x32_bf16(
                        a[mt], bfr[nt][kk], acc[mt][nt], 0, 0, 0);
        }
#pragma unroll
        for (int mt = 0; mt < 4; ++mt)
#pragma unroll
            for (int r = 0; r < 4; ++r) {
                float z0 = acc[mt][0][r] + c0;
                z0 = z0 > 0.f ? z0 : LRELU * z0;
                float z1 = acc[mt][1][r] + c1;
                z1 = z1 > 0.f ? z1 : LRELU * z1;
                float s = w0 * z0 + w1 * z1;
                s = xorReduce16(s);
                if (lo16 == 0) swave[w][mt * 16 + quad * 4 + r] = s;
            }
        __syncthreads();
        if (tid < 64)
            lgL[tid] = san(swave[0][tid] + swave[1][tid] + swave[2][tid] + swave[3][tid]);
        __syncthreads();
#pragma unroll
        for (int it = 0; it < 16; ++it) {
            int idx = tid + 256 * it;
            int nl = idx >> 7, h = idx & 127;
            int node = tile * 32 + nl;
            if (node < NN) {
                float g0 = lgL[2 * nl], g1 = lgL[2 * nl + 1];
                float mm = fmaxf(g0, g1);
                float e0 = expf(g0 - mm), e1 = expf(g1 - mm);
                float inv = 1.f / (e0 + e1);
                float xv = ldf(x, node * HID + h, fx);
                float sv = b2f(smb[node * HID + h]);
                stf(outx, node * HID + h, san((e0 * xv + e1 * sv) * inv), fo);
            }
        }
    }
}

// ---------------------------------------------------------------- CSR build
__global__ void count_kernel(const int* __restrict__ ei, const int* __restrict__ flags,
                             int* __restrict__ counts) {
    const int is64e = flags[4];
    for (int e = blockIdx.x * blockDim.x + threadIdx.x; e < NE; e += gridDim.x * blockDim.x) {
        int tail = clampi(idx_at(ei, NE + e, is64e), NN);
        atomicAdd(&counts[tail], 1);
    }
}

__global__ void scan_kernel(const int* __restrict__ counts, int* __restrict__ offs,
                            int* __restrict__ cursor) {
    __shared__ int buf[1024];
    int t = threadIdx.x;
    const int C = (NN + 1023) / 1024;
    int lo = t * C, hi = lo + C;
    if (lo > NN) lo = NN;
    if (hi > NN) hi = NN;
    int tot = 0;
    for (int i = lo; i < hi; ++i) tot += counts[i];
    buf[t] = tot;
    __syncthreads();
    for (int off = 1; off < 1024; off <<= 1) {
        int add = (t >= off) ? buf[t - off] : 0;
        __syncthreads();
        buf[t] += add;
        __syncthreads();
    }
    int base = buf[t] - tot;
    int run = 0;
    for (int i = lo; i < hi; ++i) {
        int v = base + run;
        offs[i] = v;
        cursor[i] = v;
        run += counts[i];
    }
    if (t == 1023) offs[NN] = buf[1023];
}

// scatter: assign CSR position, record pos[e] and packed (head, rel)
__global__ void scatter_kernel(const int* __restrict__ ei, const int* __restrict__ ea,
                               const int* __restrict__ flags,
                               int* __restrict__ cursor, int* __restrict__ pos,
                               unsigned int* __restrict__ hrcsr) {
    const int is64e = flags[4], is64a = flags[5];
    for (int e = blockIdx.x * blockDim.x + threadIdx.x; e < NE; e += gridDim.x * blockDim.x) {
        int tail = clampi(idx_at(ei, NE + e, is64e), NN);
        int head = clampi(idx_at(ei, e, is64e), NN);
        int rel = clampi(idx_at(ea, e, is64a), NR);
        int p = atomicAdd(&cursor[tail], 1);
        if (p >= 0 && p < NE) {
            pos[e] = p;
            hrcsr[p] = (unsigned int)head | ((unsigned int)rel << 16);
        }
    }
}

// ---------------------------------------------------------------- node softmax + aggregation (CSR-contiguous)
__global__ __launch_bounds__(256) void node_aggr_kernel(
        const bf16* __restrict__ Xmb, const bf16* __restrict__ Rmb,
        const int* __restrict__ offs, const unsigned int* __restrict__ hrcsr,
        const float* __restrict__ ccsr, bf16* __restrict__ smb) {
    __shared__ float redm[2][2], redl[2][2];
    int tid = threadIdx.x;
    int sub = tid >> 7;           // node within block
    int h = tid & 127;
    int wh = (tid >> 6) & 1;      // wave within half
    int lane = tid & 63;
    int node = blockIdx.x * 2 + sub;
    int s = offs[node], en = offs[node + 1];

    float m = -INFINITY;
    for (int i = s + h; i < en; i += 128) m = fmaxf(m, ccsr[i]);
    m = waveMax(m);
    if (lane == 0) redm[sub][wh] = m;
    __syncthreads();
    m = fmaxf(redm[sub][0], redm[sub][1]);

    float lsum = 0.f;
    for (int i = s + h; i < en; i += 128) lsum += expf(ccsr[i] - m);
    lsum = waveSum(lsum);
    if (lane == 0) redl[sub][wh] = lsum;
    __syncthreads();
    float inv = 1.f / (redl[sub][0] + redl[sub][1] + 1e-16f);

    float acc = 0.f;
    int i = s;
    for (; i + 2 <= en; i += 2) {
        unsigned int hr0 = hrcsr[i], hr1 = hrcsr[i + 1];
        float cc0 = ccsr[i], cc1 = ccsr[i + 1];
        float a0 = b2f(Xmb[(hr0 & 0xffffu) * HID + h]) + b2f(Rmb[(hr0 >> 16) * HID + h]);
        float a1 = b2f(Xmb[(hr1 & 0xffffu) * HID + h]) + b2f(Rmb[(hr1 >> 16) * HID + h]);
        acc += expf(cc0 - m) * tanhf(a0) + expf(cc1 - m) * tanhf(a1);
    }
    if (i < en) {
        unsigned int hr0 = hrcsr[i];
        float a0 = b2f(Xmb[(hr0 & 0xffffu) * HID + h]) + b2f(Rmb[(hr0 >> 16) * HID + h]);
        acc += expf(ccsr[i] - m) * tanhf(a0);
    }
    smb[node * HID + h] = f2b(san(acc * inv));
}

extern "C" void kernel_launch(void* const* d_in, const int* in_sizes, int n_in,
                              void* d_out, int out_size, void* d_ws, size_t ws_size,
                              hipStream_t stream) {
    const void* x     = d_in[0];
    const void* r     = d_in[1];
    const void* qc    = d_in[2];
    const void* fq    = d_in[3];
    const int*  ei    = (const int*)d_in[4];
    const int*  ea    = (const int*)d_in[5];
    const void* Wmess = d_in[6];
    const void* bmess = d_in[7];
    const void* Wmatt = d_in[8];
    const void* bmatt = d_in[9];
    const void* maw   = d_in[10];
    const void* Wxatt = d_in[11];
    const void* bxatt = d_in[12];
    const void* xaw   = d_in[13];
    const void* gamma = d_in[14];
    const void* beta  = d_in[15];

    // ws layout (~34 MB)
    int*          flags  = (int*)d_ws;                     // 16
    int*          counts = flags + 16;                     // NN
    int*          offs   = counts + NN;                    // NN+1
    int*          cursor = offs + NN + 1;                  // NN (+3 pad)
    int*          pos    = cursor + NN + 3;                // NE
    unsigned int* hrcsr  = (unsigned int*)(pos + NE);      // NE
    float*        ccsr   = (float*)(hrcsr + NE);           // NE
    float*        rnorm  = ccsr + NE;                      // NR*HID
    float*        cmatt  = rnorm + (size_t)NR * HID;       // HID
    float*        cxatt  = cmatt + HID;                    // HID
    bf16*         Rmb    = (bf16*)(cxatt + HID);           // NR*HID
    bf16*         Xmb    = Rmb + (size_t)NR * HID;         // NN*HID
    bf16*         smb    = Xmb + (size_t)NN * HID;         // NN*HID

    hipMemsetAsync(counts, 0, NN * sizeof(int), stream);

    DetectArr da;
    const void* ps[16] = {x, r, qc, fq, ei, ea, Wmess, bmess, Wmatt, bmatt, maw,
                          Wxatt, bxatt, xaw, gamma, beta};
    int szs[16] = {NN * HID, NR * HID, HID, HID, 2 * NE, NE, 2 * HID * HID, HID,
                   2 * HID * HID, HID, HID, 2 * HID * HID, HID, HID, HID, HID};
    for (int i = 0; i < 16; ++i) {
        da.p[i] = ps[i];
        da.sz[i] = szs[i];
        da.kind[i] = (i == 4 || i == 5) ? 1 : 0;
    }
    detect_all<<<16, 64, 0, stream>>>(da, flags);

    bn_kernel<<<1, 1024, 0, stream>>>(r, gamma, beta, flags, rnorm, d_out);
    precomp_kernel<<<1, HID, 0, stream>>>(Wmatt, bmatt, qc, Wxatt, bxatt, fq, flags,
                                          cmatt, cxatt);
    rm_kernel<<<NR, HID, 0, stream>>>(Wmess, bmess, flags, rnorm, Rmb);
    xm_mfma<<<512, 256, 0, stream>>>(x, Wmess, flags, Xmb);
    count_kernel<<<1024, 256, 0, stream>>>(ei, flags, counts);
    scan_kernel<<<1, 1024, 0, stream>>>(counts, offs, cursor);
    scatter_kernel<<<1024, 256, 0, stream>>>(ei, ea, flags, cursor, pos, hrcsr);
    edge_coeff_mfma<<<2048, 256, 0, stream>>>(Xmb, Rmb, Wmatt, cmatt, maw, ei, ea, flags,
                                              pos, ccsr);
    node_aggr_kernel<<<NN / 2, 256, 0, stream>>>(Xmb, Rmb, offs, hrcsr, ccsr, smb);
    gate_mfma<<<512, 256, 0, stream>>>(x, smb, Wxatt, cxatt, xaw, flags, d_out);
}

// Round 7
// 586.875 us; speedup vs baseline: 3.0401x; 1.2643x over previous
//
#include <hip/hip_runtime.h>
#include <hip/hip_bf16.h>

#define HID 128
#define NN 50000
#define NR 500
#define NE 625000
#define LRELU 0.01f

typedef __hip_bfloat16 bf16;
typedef __attribute__((ext_vector_type(8))) short short8;
typedef __attribute__((ext_vector_type(4))) float float4_;

__device__ __forceinline__ float b2f(bf16 v) { return __bfloat162float(v); }
__device__ __forceinline__ bf16 f2b(float v) { return __float2bfloat16(v); }

__device__ __forceinline__ float san(float v) {
    return (v == v && v > -1e30f && v < 1e30f) ? v : 0.f;
}

// fast tanh: 1 - 2/(e^{2x}+1). v_exp + v_rcp; handles +-inf correctly.
__device__ __forceinline__ float ftanh(float a) {
    float e = __expf(2.f * a);
    return 1.f - 2.f * __builtin_amdgcn_rcpf(e + 1.f);
}

__device__ __forceinline__ float ldf(const void* p, int i, int f32) {
    return f32 ? ((const float*)p)[i] : b2f(((const bf16*)p)[i]);
}
__device__ __forceinline__ void stf(void* p, int i, float v, int f32) {
    if (f32) ((float*)p)[i] = v;
    else ((bf16*)p)[i] = f2b(v);
}

__device__ __forceinline__ int clampi(int v, int hi) {
    return v < 0 ? 0 : (v >= hi ? hi - 1 : v);
}
__device__ __forceinline__ int idx_at(const int* p, int i, int is64) {
    return p[is64 ? (2 * i) : i];
}

__device__ __forceinline__ unsigned short bfbits(float v) {
    bf16 h = f2b(v);
    return *(unsigned short*)&h;
}
__device__ __forceinline__ unsigned int packbf2(float a, float b) {
    return (unsigned int)bfbits(a) | ((unsigned int)bfbits(b) << 16);
}
__device__ __forceinline__ float bflo(unsigned int u) { return __uint_as_float(u << 16); }
__device__ __forceinline__ float bfhi(unsigned int u) { return __uint_as_float(u & 0xffff0000u); }

__device__ __forceinline__ float xorReduce16(float v) {
    v += __shfl_xor(v, 1, 64);
    v += __shfl_xor(v, 2, 64);
    v += __shfl_xor(v, 4, 64);
    v += __shfl_xor(v, 8, 64);
    return v;
}
__device__ __forceinline__ float waveMax(float v) {
#pragma unroll
    for (int o = 1; o < 64; o <<= 1) v = fmaxf(v, __shfl_xor(v, o, 64));
    return v;
}
__device__ __forceinline__ float waveSum(float v) {
#pragma unroll
    for (int o = 1; o < 64; o <<= 1) v += __shfl_xor(v, o, 64);
    return v;
}

// ---------------------------------------------------------------- consolidated dtype detect
struct DetectArr {
    const void* p[16];
    int sz[16];
    int kind[16];
};

__global__ void detect_all(DetectArr d, int* __restrict__ flags) {
    int b = blockIdx.x;
    if (d.kind[b] == 1) {
        if (threadIdx.x == 0) {
            const int* q = (const int*)d.p[b];
            int o = 0;
            for (int i = 0; i < 64; ++i) o |= q[2 * i + 1];
            flags[b] = (o == 0) ? 1 : 0;
        }
        return;
    }
    __shared__ int sb[64], sf[64];
    const unsigned int* w = (const unsigned int*)d.p[b];
    int K = d.sz[b] >> 1;
    if (K > 4096) K = 4096;
    int bv = 0, fv = 0;
    for (int i = threadIdx.x; i < K; i += 64) {
        unsigned int x = w[i];
        unsigned int lo = x & 0xFFFFu, hi = x >> 16;
        if (lo == 0u) {
            if (hi) fv++;
        } else {
            unsigned int e = (lo >> 7) & 0xFFu;
            if (e >= 90u && e <= 160u) bv++;
            else fv++;
        }
    }
    sb[threadIdx.x] = bv; sf[threadIdx.x] = fv;
    __syncthreads();
    if (threadIdx.x == 0) {
        int B = 0, F = 0;
        for (int i = 0; i < 64; ++i) { B += sb[i]; F += sf[i]; }
        flags[b] = (F > B) ? 1 : 0;
    }
}

// ---------------------------------------------------------------- BatchNorm over r
__global__ void bn_kernel(const void* __restrict__ r, const void* __restrict__ gamma,
                          const void* __restrict__ beta, const int* __restrict__ flags,
                          float* __restrict__ rnorm, void* __restrict__ out_base) {
    __shared__ float sb[1024], sq[1024];
    __shared__ float muL[HID], scL[HID], beL[HID];
    const int fr = flags[1], fg = flags[14], fb = flags[15], fo = flags[0];
    int tid = threadIdx.x;
    int rr = tid >> 7, h = tid & 127;
    float s = 0.f, ss = 0.f;
    for (int i = rr; i < NR; i += 8) {
        float v = ldf(r, i * HID + h, fr);
        s += v; ss += v * v;
    }
    sb[tid] = s; sq[tid] = ss;
    __syncthreads();
    if (tid < HID) {
        float S = 0.f, SS = 0.f;
        for (int j = 0; j < 8; ++j) { S += sb[j * HID + tid]; SS += sq[j * HID + tid]; }
        float mu = S / NR;
        float var = SS / NR - mu * mu;
        if (var < 0.f) var = 0.f;
        muL[tid] = mu;
        scL[tid] = ldf(gamma, tid, fg) * rsqrtf(var + 1e-5f);
        beL[tid] = ldf(beta, tid, fb);
    }
    __syncthreads();
    float mu = muL[h], sc = scL[h], be = beL[h];
    for (int i = rr; i < NR; i += 8) {
        float v = san((ldf(r, i * HID + h, fr) - mu) * sc + be);
        rnorm[i * HID + h] = v;
        stf(out_base, NN * HID + i * HID + h, v, fo);
    }
}

// ---------------------------------------------------------------- edge-constant vectors
__global__ void precomp_kernel(const void* __restrict__ Wmatt, const void* __restrict__ bmatt,
                               const void* __restrict__ qc,
                               const void* __restrict__ Wxatt, const void* __restrict__ bxatt,
                               const void* __restrict__ fq, const int* __restrict__ flags,
                               float* __restrict__ cmatt, float* __restrict__ cxatt) {
    __shared__ float qcs[HID], fqs[HID];
    const int fWm = flags[8], fbm = flags[9], fqc = flags[2];
    const int fWx = flags[11], fbx = flags[12], ffq = flags[3];
    int h = threadIdx.x;
    qcs[h] = ldf(qc, h, fqc);
    fqs[h] = ldf(fq, h, ffq);
    __syncthreads();
    float a = ldf(bmatt, h, fbm), b = ldf(bxatt, h, fbx);
    for (int k = 0; k < HID; ++k) {
        a += ldf(Wmatt, h * 2 * HID + HID + k, fWm) * qcs[k];
        b += ldf(Wxatt, h * 2 * HID + HID + k, fWx) * fqs[k];
    }
    cmatt[h] = san(a);
    cxatt[h] = san(b);
}

// ---------------------------------------------------------------- Rmb[rel,h] (bf16)
__global__ void rm_kernel(const void* __restrict__ Wmess, const void* __restrict__ bmess,
                          const int* __restrict__ flags,
                          const float* __restrict__ rnorm, bf16* __restrict__ Rmb) {
    __shared__ float rl[HID];
    const int fW = flags[6], fb = flags[7];
    int rel = blockIdx.x, h = threadIdx.x;
    rl[h] = rnorm[rel * HID + h];
    __syncthreads();
    float a = ldf(bmess, h, fb);
    for (int k = 0; k < HID; ++k)
        a += ldf(Wmess, h * 2 * HID + HID + k, fW) * rl[k];
    Rmb[rel * HID + h] = f2b(san(a));
}

// ================================================================ MFMA kernels
#define MLDA 136

// vectorized B-fragment load: W row n, k = k0..k0+7 (fp32 or bf16)
__device__ __forceinline__ short8 load_bfrag(const void* W, int n, int k0, int f32) {
    short8 b;
    if (f32) {
        const float* Wf = (const float*)W + (size_t)n * 2 * HID + k0;
        float4 u0 = *(const float4*)Wf;
        float4 u1 = *(const float4*)(Wf + 4);
        b[0] = (short)bfbits(u0.x); b[1] = (short)bfbits(u0.y);
        b[2] = (short)bfbits(u0.z); b[3] = (short)bfbits(u0.w);
        b[4] = (short)bfbits(u1.x); b[5] = (short)bfbits(u1.y);
        b[6] = (short)bfbits(u1.z); b[7] = (short)bfbits(u1.w);
    } else {
        b = *(const short8*)((const bf16*)W + (size_t)n * 2 * HID + k0);
    }
    return b;
}

// ---------------------------------------------------------------- Xm = x @ Wmess[:, :128]^T (persistent)
__global__ __launch_bounds__(256, 4) void xm_mfma(const void* __restrict__ x,
                                                  const void* __restrict__ Wmess,
                                                  const int* __restrict__ flags,
                                                  bf16* __restrict__ Xmb) {
    __shared__ short ml[64 * MLDA];
    const int fx = flags[0], fW = flags[6];
    int tid = threadIdx.x;
    int l = tid & 63, w = tid >> 6;
    int quad = l >> 4, lo16 = l & 15;
    int nbase = w * 32;
    short8 bfr[2][4];
#pragma unroll
    for (int nt = 0; nt < 2; ++nt)
#pragma unroll
        for (int kk = 0; kk < 4; ++kk)
            bfr[nt][kk] = load_bfrag(Wmess, nbase + nt * 16 + lo16, kk * 32 + quad * 8, fW);

    const int ntiles = (NN + 63) / 64;
    for (int tile = blockIdx.x; tile < ntiles; tile += gridDim.x) {
        __syncthreads();
#pragma unroll
        for (int p = 0; p < 8; ++p) {
            int rl_ = p * 8 + (tid >> 5);
            int node = clampi(tile * 64 + rl_, NN);
            int k4 = (tid & 31) * 4;
            unsigned int o0, o1;
            if (fx) {
                float4 v = *(const float4*)((const float*)x + (size_t)node * HID + k4);
                o0 = packbf2(v.x, v.y);
                o1 = packbf2(v.z, v.w);
            } else {
                uint2 u = *(const uint2*)((const bf16*)x + (size_t)node * HID + k4);
                o0 = u.x; o1 = u.y;
            }
            unsigned int* dst = (unsigned int*)&ml[rl_ * MLDA + k4];
            dst[0] = o0; dst[1] = o1;
        }
        __syncthreads();
        float4_ acc[4][2];
#pragma unroll
        for (int mt = 0; mt < 4; ++mt)
#pragma unroll
            for (int nt = 0; nt < 2; ++nt)
                acc[mt][nt] = (float4_){0.f, 0.f, 0.f, 0.f};
#pragma unroll
        for (int kk = 0; kk < 4; ++kk) {
            short8 a[4];
#pragma unroll
            for (int mt = 0; mt < 4; ++mt)
                a[mt] = *(const short8*)&ml[(mt * 16 + lo16) * MLDA + kk * 32 + quad * 8];
#pragma unroll
            for (int mt = 0; mt < 4; ++mt)
#pragma unroll
                for (int nt = 0; nt < 2; ++nt)
                    acc[mt][nt] = __builtin_amdgcn_mfma_f32_16x16x32_bf16(
                        a[mt], bfr[nt][kk], acc[mt][nt], 0, 0, 0);
        }
#pragma unroll
        for (int mt = 0; mt < 4; ++mt)
#pragma unroll
            for (int nt = 0; nt < 2; ++nt)
#pragma unroll
                for (int r = 0; r < 4; ++r) {
                    int node = tile * 64 + mt * 16 + quad * 4 + r;
                    if (node < NN)
                        Xmb[node * HID + nbase + nt * 16 + lo16] = f2b(san(acc[mt][nt][r]));
                }
    }
}

// ---------------------------------------------------------------- edge logits (persistent, all-resident, CSR-ordered out)
__global__ __launch_bounds__(256, 6) void edge_coeff_mfma(
        const bf16* __restrict__ Xmb, const bf16* __restrict__ Rmb,
        const void* __restrict__ Wmatt, const float* __restrict__ cmatt,
        const void* __restrict__ maw,
        const int* __restrict__ ei, const int* __restrict__ ea,
        const int* __restrict__ flags, const int* __restrict__ pos,
        float* __restrict__ ccsr) {
    __shared__ short ml[64 * MLDA];
    __shared__ float swave[4][64];
    const int fWm = flags[8], fmw = flags[10];
    const int is64e = flags[4], is64a = flags[5];
    int tid = threadIdx.x;
    int l = tid & 63, w = tid >> 6;
    int quad = l >> 4, lo16 = l & 15;
    int nbase = w * 32;
    short8 bfr[2][4];
#pragma unroll
    for (int nt = 0; nt < 2; ++nt)
#pragma unroll
        for (int kk = 0; kk < 4; ++kk)
            bfr[nt][kk] = load_bfrag(Wmatt, nbase + nt * 16 + lo16, kk * 32 + quad * 8, fWm);

    int n0 = nbase + lo16, n1 = n0 + 16;
    float c0 = cmatt[n0], c1 = cmatt[n1];
    float w0 = ldf(maw, n0, fmw), w1 = ldf(maw, n1, fmw);

    const int ntiles = (NE + 63) / 64;
    const int seg = tid & 15;         // 16B segment within row
    const int rowsub = tid >> 4;      // 0..15
    for (int T = blockIdx.x; T < ntiles; T += gridDim.x) {
        __syncthreads();
        // stage mess = tanh(Xm[head]+Rm[rel]) for 64 edges, 16B/lane
#pragma unroll
        for (int p = 0; p < 4; ++p) {
            int el = p * 16 + rowsub;
            int e = T * 64 + el;
            int ec = e < NE ? e : NE - 1;
            int head = clampi(idx_at(ei, ec, is64e), NN);
            int rel = clampi(idx_at(ea, ec, is64a), NR);
            int k8 = seg * 8;
            uint4 xv = *(const uint4*)&Xmb[head * HID + k8];
            uint4 rv = *(const uint4*)&Rmb[rel * HID + k8];
            uint4 o;
            o.x = packbf2(ftanh(bflo(xv.x) + bflo(rv.x)), ftanh(bfhi(xv.x) + bfhi(rv.x)));
            o.y = packbf2(ftanh(bflo(xv.y) + bflo(rv.y)), ftanh(bfhi(xv.y) + bfhi(rv.y)));
            o.z = packbf2(ftanh(bflo(xv.z) + bflo(rv.z)), ftanh(bfhi(xv.z) + bfhi(rv.z)));
            o.w = packbf2(ftanh(bflo(xv.w) + bflo(rv.w)), ftanh(bfhi(xv.w) + bfhi(rv.w)));
            *(uint4*)&ml[el * MLDA + k8] = o;
        }
        __syncthreads();
        float4_ acc[4][2];
#pragma unroll
        for (int mt = 0; mt < 4; ++mt)
#pragma unroll
            for (int nt = 0; nt < 2; ++nt)
                acc[mt][nt] = (float4_){0.f, 0.f, 0.f, 0.f};
#pragma unroll
        for (int kk = 0; kk < 4; ++kk) {
            short8 a[4];
#pragma unroll
            for (int mt = 0; mt < 4; ++mt)
                a[mt] = *(const short8*)&ml[(mt * 16 + lo16) * MLDA + kk * 32 + quad * 8];
#pragma unroll
            for (int mt = 0; mt < 4; ++mt)
#pragma unroll
                for (int nt = 0; nt < 2; ++nt)
                    acc[mt][nt] = __builtin_amdgcn_mfma_f32_16x16x32_bf16(
                        a[mt], bfr[nt][kk], acc[mt][nt], 0, 0, 0);
        }
#pragma unroll
        for (int mt = 0; mt < 4; ++mt)
#pragma unroll
            for (int r = 0; r < 4; ++r) {
                float z0 = acc[mt][0][r] + c0;
                z0 = z0 > 0.f ? z0 : LRELU * z0;
                float z1 = acc[mt][1][r] + c1;
                z1 = z1 > 0.f ? z1 : LRELU * z1;
                float s = w0 * z0 + w1 * z1;
                s = xorReduce16(s);
                if (lo16 == 0) swave[w][mt * 16 + quad * 4 + r] = s;
            }
        __syncthreads();
        if (tid < 64) {
            int e = T * 64 + tid;
            if (e < NE) {
                float v = san(swave[0][tid] + swave[1][tid] + swave[2][tid] + swave[3][tid]);
                ccsr[pos[e]] = v;
            }
        }
    }
}

// ---------------------------------------------------------------- gate (persistent)
__global__ __launch_bounds__(256, 4) void gate_mfma(
        const void* __restrict__ x, const bf16* __restrict__ smb,
        const void* __restrict__ Wxatt, const float* __restrict__ cxatt,
        const void* __restrict__ xaw, const int* __restrict__ flags,
        void* __restrict__ outx) {
    __shared__ short ml[64 * MLDA];
    __shared__ float swave[4][64];
    __shared__ float lgL[64];
    const int fx = flags[0], fWx = flags[11], fxw = flags[13], fo = flags[0];
    int tid = threadIdx.x;
    int l = tid & 63, w = tid >> 6;
    int quad = l >> 4, lo16 = l & 15;
    int nbase = w * 32;
    short8 bfr[2][4];
#pragma unroll
    for (int nt = 0; nt < 2; ++nt)
#pragma unroll
        for (int kk = 0; kk < 4; ++kk)
            bfr[nt][kk] = load_bfrag(Wxatt, nbase + nt * 16 + lo16, kk * 32 + quad * 8, fWx);

    int n0 = nbase + lo16, n1 = n0 + 16;
    float c0 = cxatt[n0], c1 = cxatt[n1];
    float w0 = ldf(xaw, n0, fxw), w1 = ldf(xaw, n1, fxw);

    const int ntiles = (NN + 31) / 32;
    for (int tile = blockIdx.x; tile < ntiles; tile += gridDim.x) {
        __syncthreads();
#pragma unroll
        for (int p = 0; p < 8; ++p) {
            int rl_ = p * 8 + (tid >> 5);
            int node = clampi(tile * 32 + (rl_ >> 1), NN);
            int k4 = (tid & 31) * 4;
            unsigned int o0, o1;
            if (rl_ & 1) {
                uint2 u = *(const uint2*)&smb[node * HID + k4];
                o0 = u.x; o1 = u.y;
            } else if (fx) {
                float4 v = *(const float4*)((const float*)x + (size_t)node * HID + k4);
                o0 = packbf2(v.x, v.y);
                o1 = packbf2(v.z, v.w);
            } else {
                uint2 u = *(const uint2*)((const bf16*)x + (size_t)node * HID + k4);
                o0 = u.x; o1 = u.y;
            }
            unsigned int* dst = (unsigned int*)&ml[rl_ * MLDA + k4];
            dst[0] = o0; dst[1] = o1;
        }
        __syncthreads();
        float4_ acc[4][2];
#pragma unroll
        for (int mt = 0; mt < 4; ++mt)
#pragma unroll
            for (int nt = 0; nt < 2; ++nt)
                acc[mt][nt] = (float4_){0.f, 0.f, 0.f, 0.f};
#pragma unroll
        for (int kk = 0; kk < 4; ++kk) {
            short8 a[4];
#pragma unroll
            for (int mt = 0; mt < 4; ++mt)
                a[mt] = *(const short8*)&ml[(mt * 16 + lo16) * MLDA + kk * 32 + quad * 8];
#pragma unroll
            for (int mt = 0; mt < 4; ++mt)
#pragma unroll
                for (int nt = 0; nt < 2; ++nt)
                    acc[mt][nt] = __builtin_amdgcn_mfma_f32_16x16x32_bf16(
                        a[mt], bfr[nt][kk], acc[mt][nt], 0, 0, 0);
        }
#pragma unroll
        for (int mt = 0; mt < 4; ++mt)
#pragma unroll
            for (int r = 0; r < 4; ++r) {
                float z0 = acc[mt][0][r] + c0;
                z0 = z0 > 0.f ? z0 : LRELU * z0;
                float z1 = acc[mt][1][r] + c1;
                z1 = z1 > 0.f ? z1 : LRELU * z1;
                float s = w0 * z0 + w1 * z1;
                s = xorReduce16(s);
                if (lo16 == 0) swave[w][mt * 16 + quad * 4 + r] = s;
            }
        __syncthreads();
        if (tid < 64)
            lgL[tid] = san(swave[0][tid] + swave[1][tid] + swave[2][tid] + swave[3][tid]);
        __syncthreads();
#pragma unroll
        for (int it = 0; it < 16; ++it) {
            int idx = tid + 256 * it;
            int nl = idx >> 7, h = idx & 127;
            int node = tile * 32 + nl;
            if (node < NN) {
                float g0 = lgL[2 * nl], g1 = lgL[2 * nl + 1];
                float mm = fmaxf(g0, g1);
                float e0 = __expf(g0 - mm), e1 = __expf(g1 - mm);
                float inv = __builtin_amdgcn_rcpf(e0 + e1);
                float xv = ldf(x, node * HID + h, fx);
                float sv = b2f(smb[node * HID + h]);
                stf(outx, node * HID + h, san((e0 * xv + e1 * sv) * inv), fo);
            }
        }
    }
}

// ---------------------------------------------------------------- CSR build
__global__ void count_kernel(const int* __restrict__ ei, const int* __restrict__ flags,
                             int* __restrict__ counts) {
    const int is64e = flags[4];
    for (int e = blockIdx.x * blockDim.x + threadIdx.x; e < NE; e += gridDim.x * blockDim.x) {
        int tail = clampi(idx_at(ei, NE + e, is64e), NN);
        atomicAdd(&counts[tail], 1);
    }
}

__global__ void scan_kernel(const int* __restrict__ counts, int* __restrict__ offs,
                            int* __restrict__ cursor) {
    __shared__ int buf[1024];
    int t = threadIdx.x;
    const int C = (NN + 1023) / 1024;
    int lo = t * C, hi = lo + C;
    if (lo > NN) lo = NN;
    if (hi > NN) hi = NN;
    int tot = 0;
    for (int i = lo; i < hi; ++i) tot += counts[i];
    buf[t] = tot;
    __syncthreads();
    for (int off = 1; off < 1024; off <<= 1) {
        int add = (t >= off) ? buf[t - off] : 0;
        __syncthreads();
        buf[t] += add;
        __syncthreads();
    }
    int base = buf[t] - tot;
    int run = 0;
    for (int i = lo; i < hi; ++i) {
        int v = base + run;
        offs[i] = v;
        cursor[i] = v;
        run += counts[i];
    }
    if (t == 1023) offs[NN] = buf[1023];
}

__global__ void scatter_kernel(const int* __restrict__ ei, const int* __restrict__ ea,
                               const int* __restrict__ flags,
                               int* __restrict__ cursor, int* __restrict__ pos,
                               unsigned int* __restrict__ hrcsr) {
    const int is64e = flags[4], is64a = flags[5];
    for (int e = blockIdx.x * blockDim.x + threadIdx.x; e < NE; e += gridDim.x * blockDim.x) {
        int tail = clampi(idx_at(ei, NE + e, is64e), NN);
        int head = clampi(idx_at(ei, e, is64e), NN);
        int rel = clampi(idx_at(ea, e, is64a), NR);
        int p = atomicAdd(&cursor[tail], 1);
        if (p >= 0 && p < NE) {
            pos[e] = p;
            hrcsr[p] = (unsigned int)head | ((unsigned int)rel << 16);
        }
    }
}

// ---------------------------------------------------------------- node softmax + aggregation
// 64 lanes per node (2 columns/lane), 4 nodes per block
__global__ __launch_bounds__(256, 8) void node_aggr_kernel(
        const bf16* __restrict__ Xmb, const bf16* __restrict__ Rmb,
        const int* __restrict__ offs, const unsigned int* __restrict__ hrcsr,
        const float* __restrict__ ccsr, bf16* __restrict__ smb) {
    int tid = threadIdx.x;
    int sub = tid >> 6;
    int lane = tid & 63;
    int node = blockIdx.x * 4 + sub;
    if (node >= NN) return;
    int s = offs[node], en = offs[node + 1];

    float m = -INFINITY;
    for (int i = s + lane; i < en; i += 64) m = fmaxf(m, ccsr[i]);
    m = waveMax(m);
    float lsum = 0.f;
    for (int i = s + lane; i < en; i += 64) lsum += __expf(ccsr[i] - m);
    lsum = waveSum(lsum);
    float inv = 1.f / (lsum + 1e-16f);

    const int col = lane * 2;
    float acc0 = 0.f, acc1 = 0.f;
    int i = s;
    for (; i + 2 <= en; i += 2) {
        unsigned int hr0 = hrcsr[i], hr1 = hrcsr[i + 1];
        float wg0 = __expf(ccsr[i] - m), wg1 = __expf(ccsr[i + 1] - m);
        unsigned int xv0 = *(const unsigned int*)&Xmb[(hr0 & 0xffffu) * HID + col];
        unsigned int rv0 = *(const unsigned int*)&Rmb[(hr0 >> 16) * HID + col];
        unsigned int xv1 = *(const unsigned int*)&Xmb[(hr1 & 0xffffu) * HID + col];
        unsigned int rv1 = *(const unsigned int*)&Rmb[(hr1 >> 16) * HID + col];
        acc0 += wg0 * ftanh(bflo(xv0) + bflo(rv0)) + wg1 * ftanh(bflo(xv1) + bflo(rv1));
        acc1 += wg0 * ftanh(bfhi(xv0) + bfhi(rv0)) + wg1 * ftanh(bfhi(xv1) + bfhi(rv1));
    }
    if (i < en) {
        unsigned int hr0 = hrcsr[i];
        float wg0 = __expf(ccsr[i] - m);
        unsigned int xv0 = *(const unsigned int*)&Xmb[(hr0 & 0xffffu) * HID + col];
        unsigned int rv0 = *(const unsigned int*)&Rmb[(hr0 >> 16) * HID + col];
        acc0 += wg0 * ftanh(bflo(xv0) + bflo(rv0));
        acc1 += wg0 * ftanh(bfhi(xv0) + bfhi(rv0));
    }
    *(unsigned int*)&smb[node * HID + col] = packbf2(san(acc0 * inv), san(acc1 * inv));
}

extern "C" void kernel_launch(void* const* d_in, const int* in_sizes, int n_in,
                              void* d_out, int out_size, void* d_ws, size_t ws_size,
                              hipStream_t stream) {
    const void* x     = d_in[0];
    const void* r     = d_in[1];
    const void* qc    = d_in[2];
    const void* fq    = d_in[3];
    const int*  ei    = (const int*)d_in[4];
    const int*  ea    = (const int*)d_in[5];
    const void* Wmess = d_in[6];
    const void* bmess = d_in[7];
    const void* Wmatt = d_in[8];
    const void* bmatt = d_in[9];
    const void* maw   = d_in[10];
    const void* Wxatt = d_in[11];
    const void* bxatt = d_in[12];
    const void* xaw   = d_in[13];
    const void* gamma = d_in[14];
    const void* beta  = d_in[15];

    int*          flags  = (int*)d_ws;
    int*          counts = flags + 16;
    int*          offs   = counts + NN;
    int*          cursor = offs + NN + 1;
    int*          pos    = cursor + NN + 3;
    unsigned int* hrcsr  = (unsigned int*)(pos + NE);
    float*        ccsr   = (float*)(hrcsr + NE);
    float*        rnorm  = ccsr + NE;
    float*        cmatt  = rnorm + (size_t)NR * HID;
    float*        cxatt  = cmatt + HID;
    bf16*         Rmb    = (bf16*)(cxatt + HID);
    bf16*         Xmb    = Rmb + (size_t)NR * HID;
    bf16*         smb    = Xmb + (size_t)NN * HID;

    hipMemsetAsync(counts, 0, NN * sizeof(int), stream);

    DetectArr da;
    const void* ps[16] = {x, r, qc, fq, ei, ea, Wmess, bmess, Wmatt, bmatt, maw,
                          Wxatt, bxatt, xaw, gamma, beta};
    int szs[16] = {NN * HID, NR * HID, HID, HID, 2 * NE, NE, 2 * HID * HID, HID,
                   2 * HID * HID, HID, HID, 2 * HID * HID, HID, HID, HID, HID};
    for (int i = 0; i < 16; ++i) {
        da.p[i] = ps[i];
        da.sz[i] = szs[i];
        da.kind[i] = (i == 4 || i == 5) ? 1 : 0;
    }
    detect_all<<<16, 64, 0, stream>>>(da, flags);

    bn_kernel<<<1, 1024, 0, stream>>>(r, gamma, beta, flags, rnorm, d_out);
    precomp_kernel<<<1, HID, 0, stream>>>(Wmatt, bmatt, qc, Wxatt, bxatt, fq, flags,
                                          cmatt, cxatt);
    rm_kernel<<<NR, HID, 0, stream>>>(Wmess, bmess, flags, rnorm, Rmb);
    xm_mfma<<<512, 256, 0, stream>>>(x, Wmess, flags, Xmb);
    count_kernel<<<1024, 256, 0, stream>>>(ei, flags, counts);
    scan_kernel<<<1, 1024, 0, stream>>>(counts, offs, cursor);
    scatter_kernel<<<1024, 256, 0, stream>>>(ei, ea, flags, cursor, pos, hrcsr);
    edge_coeff_mfma<<<1536, 256, 0, stream>>>(Xmb, Rmb, Wmatt, cmatt, maw, ei, ea, flags,
                                              pos, ccsr);
    node_aggr_kernel<<<(NN + 3) / 4, 256, 0, stream>>>(Xmb, Rmb, offs, hrcsr, ccsr, smb);
    gate_mfma<<<512, 256, 0, stream>>>(x, smb, Wxatt, cxatt, xaw, flags, d_out);
}

// Round 8
// 453.469 us; speedup vs baseline: 3.9344x; 1.2942x over previous
//
#include <hip/hip_runtime.h>
#include <hip/hip_bf16.h>

#define HID 128
#define NN 50000
#define NR 500
#define NE 625000
#define LRELU 0.01f
#define SCAN_BLOCKS 196   // ceil(NN/256)

typedef __hip_bfloat16 bf16;
typedef __attribute__((ext_vector_type(8))) short short8;
typedef __attribute__((ext_vector_type(4))) float float4_;

__device__ __forceinline__ float b2f(bf16 v) { return __bfloat162float(v); }
__device__ __forceinline__ bf16 f2b(float v) { return __float2bfloat16(v); }

__device__ __forceinline__ float san(float v) {
    return (v == v && v > -1e30f && v < 1e30f) ? v : 0.f;
}

// fast tanh: 1 - 2/(e^{2x}+1)
__device__ __forceinline__ float ftanh(float a) {
    float e = __expf(2.f * a);
    return 1.f - 2.f * __builtin_amdgcn_rcpf(e + 1.f);
}

__device__ __forceinline__ float ldf(const void* p, int i, int f32) {
    return f32 ? ((const float*)p)[i] : b2f(((const bf16*)p)[i]);
}
__device__ __forceinline__ void stf(void* p, int i, float v, int f32) {
    if (f32) ((float*)p)[i] = v;
    else ((bf16*)p)[i] = f2b(v);
}

__device__ __forceinline__ int clampi(int v, int hi) {
    return v < 0 ? 0 : (v >= hi ? hi - 1 : v);
}
__device__ __forceinline__ int idx_at(const int* p, int i, int is64) {
    return p[is64 ? (2 * i) : i];
}

__device__ __forceinline__ unsigned short bfbits(float v) {
    bf16 h = f2b(v);
    return *(unsigned short*)&h;
}
__device__ __forceinline__ unsigned int packbf2(float a, float b) {
    return (unsigned int)bfbits(a) | ((unsigned int)bfbits(b) << 16);
}
__device__ __forceinline__ float bflo(unsigned int u) { return __uint_as_float(u << 16); }
__device__ __forceinline__ float bfhi(unsigned int u) { return __uint_as_float(u & 0xffff0000u); }

__device__ __forceinline__ float xorReduce16(float v) {
    v += __shfl_xor(v, 1, 64);
    v += __shfl_xor(v, 2, 64);
    v += __shfl_xor(v, 4, 64);
    v += __shfl_xor(v, 8, 64);
    return v;
}
__device__ __forceinline__ float waveMax(float v) {
#pragma unroll
    for (int o = 1; o < 64; o <<= 1) v = fmaxf(v, __shfl_xor(v, o, 64));
    return v;
}
__device__ __forceinline__ float waveSum(float v) {
#pragma unroll
    for (int o = 1; o < 64; o <<= 1) v += __shfl_xor(v, o, 64);
    return v;
}

// ---------------------------------------------------------------- consolidated dtype detect
struct DetectArr {
    const void* p[16];
    int sz[16];
    int kind[16];
};

__global__ void detect_all(DetectArr d, int* __restrict__ flags) {
    int b = blockIdx.x;
    if (d.kind[b] == 1) {
        if (threadIdx.x == 0) {
            const int* q = (const int*)d.p[b];
            int o = 0;
            for (int i = 0; i < 64; ++i) o |= q[2 * i + 1];
            flags[b] = (o == 0) ? 1 : 0;
        }
        return;
    }
    __shared__ int sb[64], sf[64];
    const unsigned int* w = (const unsigned int*)d.p[b];
    int K = d.sz[b] >> 1;
    if (K > 4096) K = 4096;
    int bv = 0, fv = 0;
    for (int i = threadIdx.x; i < K; i += 64) {
        unsigned int x = w[i];
        unsigned int lo = x & 0xFFFFu, hi = x >> 16;
        if (lo == 0u) {
            if (hi) fv++;
        } else {
            unsigned int e = (lo >> 7) & 0xFFu;
            if (e >= 90u && e <= 160u) bv++;
            else fv++;
        }
    }
    sb[threadIdx.x] = bv; sf[threadIdx.x] = fv;
    __syncthreads();
    if (threadIdx.x == 0) {
        int B = 0, F = 0;
        for (int i = 0; i < 64; ++i) { B += sb[i]; F += sf[i]; }
        flags[b] = (F > B) ? 1 : 0;
    }
}

// ---------------------------------------------------------------- BatchNorm: stats (1 block/column)
__global__ void bn_stats(const void* __restrict__ r, const int* __restrict__ flags,
                         float* __restrict__ stats) {
    __shared__ float sb[256], sq[256];
    const int fr = flags[1];
    int h = blockIdx.x;
    int t = threadIdx.x;
    float s = 0.f, ss = 0.f;
    for (int i = t; i < NR; i += 256) {
        float v = ldf(r, i * HID + h, fr);
        s += v; ss += v * v;
    }
    sb[t] = s; sq[t] = ss;
    __syncthreads();
    for (int o = 128; o > 0; o >>= 1) {
        if (t < o) { sb[t] += sb[t + o]; sq[t] += sq[t + o]; }
        __syncthreads();
    }
    if (t == 0) {
        float mu = sb[0] / NR;
        float var = sq[0] / NR - mu * mu;
        if (var < 0.f) var = 0.f;
        stats[h] = mu;
        stats[HID + h] = rsqrtf(var + 1e-5f);
    }
}

// ---------------------------------------------------------------- BatchNorm: apply (element-parallel)
__global__ void bn_apply(const void* __restrict__ r, const void* __restrict__ gamma,
                         const void* __restrict__ beta, const int* __restrict__ flags,
                         const float* __restrict__ stats,
                         float* __restrict__ rnorm, void* __restrict__ out_base) {
    const int fr = flags[1], fg = flags[14], fb = flags[15], fo = flags[0];
    int i = blockIdx.x * 256 + threadIdx.x;
    if (i >= NR * HID) return;
    int h = i & 127;
    float v = san((ldf(r, i, fr) - stats[h]) * stats[HID + h] * ldf(gamma, h, fg)
                  + ldf(beta, h, fb));
    rnorm[i] = v;
    stf(out_base, NN * HID + i, v, fo);
}

// ---------------------------------------------------------------- edge-constant vectors
__global__ void precomp_kernel(const void* __restrict__ Wmatt, const void* __restrict__ bmatt,
                               const void* __restrict__ qc,
                               const void* __restrict__ Wxatt, const void* __restrict__ bxatt,
                               const void* __restrict__ fq, const int* __restrict__ flags,
                               float* __restrict__ cmatt, float* __restrict__ cxatt) {
    __shared__ float qcs[HID], fqs[HID];
    const int fWm = flags[8], fbm = flags[9], fqc = flags[2];
    const int fWx = flags[11], fbx = flags[12], ffq = flags[3];
    int h = threadIdx.x;
    qcs[h] = ldf(qc, h, fqc);
    fqs[h] = ldf(fq, h, ffq);
    __syncthreads();
    float a = ldf(bmatt, h, fbm), b = ldf(bxatt, h, fbx);
    for (int k = 0; k < HID; ++k) {
        a += ldf(Wmatt, h * 2 * HID + HID + k, fWm) * qcs[k];
        b += ldf(Wxatt, h * 2 * HID + HID + k, fWx) * fqs[k];
    }
    cmatt[h] = san(a);
    cxatt[h] = san(b);
}

// ---------------------------------------------------------------- Rmb[rel,h] (bf16)
__global__ void rm_kernel(const void* __restrict__ Wmess, const void* __restrict__ bmess,
                          const int* __restrict__ flags,
                          const float* __restrict__ rnorm, bf16* __restrict__ Rmb) {
    __shared__ float rl[HID];
    const int fW = flags[6], fb = flags[7];
    int rel = blockIdx.x, h = threadIdx.x;
    rl[h] = rnorm[rel * HID + h];
    __syncthreads();
    float a = ldf(bmess, h, fb);
    for (int k = 0; k < HID; ++k)
        a += ldf(Wmess, h * 2 * HID + HID + k, fW) * rl[k];
    Rmb[rel * HID + h] = f2b(san(a));
}

// ================================================================ MFMA kernels
#define MLDA 136

__device__ __forceinline__ short8 load_bfrag(const void* W, int n, int k0, int f32) {
    short8 b;
    if (f32) {
        const float* Wf = (const float*)W + (size_t)n * 2 * HID + k0;
        float4 u0 = *(const float4*)Wf;
        float4 u1 = *(const float4*)(Wf + 4);
        b[0] = (short)bfbits(u0.x); b[1] = (short)bfbits(u0.y);
        b[2] = (short)bfbits(u0.z); b[3] = (short)bfbits(u0.w);
        b[4] = (short)bfbits(u1.x); b[5] = (short)bfbits(u1.y);
        b[6] = (short)bfbits(u1.z); b[7] = (short)bfbits(u1.w);
    } else {
        b = *(const short8*)((const bf16*)W + (size_t)n * 2 * HID + k0);
    }
    return b;
}

// ---------------------------------------------------------------- Xm = x @ Wmess[:, :128]^T (persistent)
__global__ __launch_bounds__(256, 4) void xm_mfma(const void* __restrict__ x,
                                                  const void* __restrict__ Wmess,
                                                  const int* __restrict__ flags,
                                                  bf16* __restrict__ Xmb) {
    __shared__ short ml[64 * MLDA];
    const int fx = flags[0], fW = flags[6];
    int tid = threadIdx.x;
    int l = tid & 63, w = tid >> 6;
    int quad = l >> 4, lo16 = l & 15;
    int nbase = w * 32;
    short8 bfr[2][4];
#pragma unroll
    for (int nt = 0; nt < 2; ++nt)
#pragma unroll
        for (int kk = 0; kk < 4; ++kk)
            bfr[nt][kk] = load_bfrag(Wmess, nbase + nt * 16 + lo16, kk * 32 + quad * 8, fW);

    const int ntiles = (NN + 63) / 64;
    for (int tile = blockIdx.x; tile < ntiles; tile += gridDim.x) {
        __syncthreads();
#pragma unroll
        for (int p = 0; p < 8; ++p) {
            int rl_ = p * 8 + (tid >> 5);
            int node = clampi(tile * 64 + rl_, NN);
            int k4 = (tid & 31) * 4;
            unsigned int o0, o1;
            if (fx) {
                float4 v = *(const float4*)((const float*)x + (size_t)node * HID + k4);
                o0 = packbf2(v.x, v.y);
                o1 = packbf2(v.z, v.w);
            } else {
                uint2 u = *(const uint2*)((const bf16*)x + (size_t)node * HID + k4);
                o0 = u.x; o1 = u.y;
            }
            unsigned int* dst = (unsigned int*)&ml[rl_ * MLDA + k4];
            dst[0] = o0; dst[1] = o1;
        }
        __syncthreads();
        float4_ acc[4][2];
#pragma unroll
        for (int mt = 0; mt < 4; ++mt)
#pragma unroll
            for (int nt = 0; nt < 2; ++nt)
                acc[mt][nt] = (float4_){0.f, 0.f, 0.f, 0.f};
#pragma unroll
        for (int kk = 0; kk < 4; ++kk) {
            short8 a[4];
#pragma unroll
            for (int mt = 0; mt < 4; ++mt)
                a[mt] = *(const short8*)&ml[(mt * 16 + lo16) * MLDA + kk * 32 + quad * 8];
#pragma unroll
            for (int mt = 0; mt < 4; ++mt)
#pragma unroll
                for (int nt = 0; nt < 2; ++nt)
                    acc[mt][nt] = __builtin_amdgcn_mfma_f32_16x16x32_bf16(
                        a[mt], bfr[nt][kk], acc[mt][nt], 0, 0, 0);
        }
#pragma unroll
        for (int mt = 0; mt < 4; ++mt)
#pragma unroll
            for (int nt = 0; nt < 2; ++nt)
#pragma unroll
                for (int r = 0; r < 4; ++r) {
                    int node = tile * 64 + mt * 16 + quad * 4 + r;
                    if (node < NN)
                        Xmb[node * HID + nbase + nt * 16 + lo16] = f2b(san(acc[mt][nt][r]));
                }
    }
}

// ---------------------------------------------------------------- edge logits: CSR-slot order (no pos indirection)
__global__ __launch_bounds__(256, 6) void edge_coeff_mfma(
        const bf16* __restrict__ Xmb, const bf16* __restrict__ Rmb,
        const void* __restrict__ Wmatt, const float* __restrict__ cmatt,
        const void* __restrict__ maw, const unsigned int* __restrict__ hrcsr,
        const int* __restrict__ flags, float* __restrict__ ccsr) {
    __shared__ short ml[64 * MLDA];
    __shared__ float swave[4][64];
    const int fWm = flags[8], fmw = flags[10];
    int tid = threadIdx.x;
    int l = tid & 63, w = tid >> 6;
    int quad = l >> 4, lo16 = l & 15;
    int nbase = w * 32;
    short8 bfr[2][4];
#pragma unroll
    for (int nt = 0; nt < 2; ++nt)
#pragma unroll
        for (int kk = 0; kk < 4; ++kk)
            bfr[nt][kk] = load_bfrag(Wmatt, nbase + nt * 16 + lo16, kk * 32 + quad * 8, fWm);

    int n0 = nbase + lo16, n1 = n0 + 16;
    float c0 = cmatt[n0], c1 = cmatt[n1];
    float w0 = ldf(maw, n0, fmw), w1 = ldf(maw, n1, fmw);

    const int ntiles = (NE + 63) / 64;
    const int seg = tid & 15;
    const int rowsub = tid >> 4;
    for (int T = blockIdx.x; T < ntiles; T += gridDim.x) {
        __syncthreads();
#pragma unroll
        for (int p = 0; p < 4; ++p) {
            int el = p * 16 + rowsub;
            int slot = T * 64 + el;
            unsigned int hr = hrcsr[slot < NE ? slot : NE - 1];
            int head = hr & 0xffffu, rel = hr >> 16;
            int k8 = seg * 8;
            uint4 xv = *(const uint4*)&Xmb[head * HID + k8];
            uint4 rv = *(const uint4*)&Rmb[rel * HID + k8];
            uint4 o;
            o.x = packbf2(ftanh(bflo(xv.x) + bflo(rv.x)), ftanh(bfhi(xv.x) + bfhi(rv.x)));
            o.y = packbf2(ftanh(bflo(xv.y) + bflo(rv.y)), ftanh(bfhi(xv.y) + bfhi(rv.y)));
            o.z = packbf2(ftanh(bflo(xv.z) + bflo(rv.z)), ftanh(bfhi(xv.z) + bfhi(rv.z)));
            o.w = packbf2(ftanh(bflo(xv.w) + bflo(rv.w)), ftanh(bfhi(xv.w) + bfhi(rv.w)));
            *(uint4*)&ml[el * MLDA + k8] = o;
        }
        __syncthreads();
        float4_ acc[4][2];
#pragma unroll
        for (int mt = 0; mt < 4; ++mt)
#pragma unroll
            for (int nt = 0; nt < 2; ++nt)
                acc[mt][nt] = (float4_){0.f, 0.f, 0.f, 0.f};
#pragma unroll
        for (int kk = 0; kk < 4; ++kk) {
            short8 a[4];
#pragma unroll
            for (int mt = 0; mt < 4; ++mt)
                a[mt] = *(const short8*)&ml[(mt * 16 + lo16) * MLDA + kk * 32 + quad * 8];
#pragma unroll
            for (int mt = 0; mt < 4; ++mt)
#pragma unroll
                for (int nt = 0; nt < 2; ++nt)
                    acc[mt][nt] = __builtin_amdgcn_mfma_f32_16x16x32_bf16(
                        a[mt], bfr[nt][kk], acc[mt][nt], 0, 0, 0);
        }
#pragma unroll
        for (int mt = 0; mt < 4; ++mt)
#pragma unroll
            for (int r = 0; r < 4; ++r) {
                float z0 = acc[mt][0][r] + c0;
                z0 = z0 > 0.f ? z0 : LRELU * z0;
                float z1 = acc[mt][1][r] + c1;
                z1 = z1 > 0.f ? z1 : LRELU * z1;
                float s = w0 * z0 + w1 * z1;
                s = xorReduce16(s);
                if (lo16 == 0) swave[w][mt * 16 + quad * 4 + r] = s;
            }
        __syncthreads();
        if (tid < 64) {
            int slot = T * 64 + tid;
            if (slot < NE)
                ccsr[slot] = san(swave[0][tid] + swave[1][tid] + swave[2][tid] + swave[3][tid]);
        }
    }
}

// ---------------------------------------------------------------- gate (persistent)
__global__ __launch_bounds__(256, 4) void gate_mfma(
        const void* __restrict__ x, const bf16* __restrict__ smb,
        const void* __restrict__ Wxatt, const float* __restrict__ cxatt,
        const void* __restrict__ xaw, const int* __restrict__ flags,
        void* __restrict__ outx) {
    __shared__ short ml[64 * MLDA];
    __shared__ float swave[4][64];
    __shared__ float lgL[64];
    const int fx = flags[0], fWx = flags[11], fxw = flags[13], fo = flags[0];
    int tid = threadIdx.x;
    int l = tid & 63, w = tid >> 6;
    int quad = l >> 4, lo16 = l & 15;
    int nbase = w * 32;
    short8 bfr[2][4];
#pragma unroll
    for (int nt = 0; nt < 2; ++nt)
#pragma unroll
        for (int kk = 0; kk < 4; ++kk)
            bfr[nt][kk] = load_bfrag(Wxatt, nbase + nt * 16 + lo16, kk * 32 + quad * 8, fWx);

    int n0 = nbase + lo16, n1 = n0 + 16;
    float c0 = cxatt[n0], c1 = cxatt[n1];
    float w0 = ldf(xaw, n0, fxw), w1 = ldf(xaw, n1, fxw);

    const int ntiles = (NN + 31) / 32;
    for (int tile = blockIdx.x; tile < ntiles; tile += gridDim.x) {
        __syncthreads();
#pragma unroll
        for (int p = 0; p < 8; ++p) {
            int rl_ = p * 8 + (tid >> 5);
            int node = clampi(tile * 32 + (rl_ >> 1), NN);
            int k4 = (tid & 31) * 4;
            unsigned int o0, o1;
            if (rl_ & 1) {
                uint2 u = *(const uint2*)&smb[node * HID + k4];
                o0 = u.x; o1 = u.y;
            } else if (fx) {
                float4 v = *(const float4*)((const float*)x + (size_t)node * HID + k4);
                o0 = packbf2(v.x, v.y);
                o1 = packbf2(v.z, v.w);
            } else {
                uint2 u = *(const uint2*)((const bf16*)x + (size_t)node * HID + k4);
                o0 = u.x; o1 = u.y;
            }
            unsigned int* dst = (unsigned int*)&ml[rl_ * MLDA + k4];
            dst[0] = o0; dst[1] = o1;
        }
        __syncthreads();
        float4_ acc[4][2];
#pragma unroll
        for (int mt = 0; mt < 4; ++mt)
#pragma unroll
            for (int nt = 0; nt < 2; ++nt)
                acc[mt][nt] = (float4_){0.f, 0.f, 0.f, 0.f};
#pragma unroll
        for (int kk = 0; kk < 4; ++kk) {
            short8 a[4];
#pragma unroll
            for (int mt = 0; mt < 4; ++mt)
                a[mt] = *(const short8*)&ml[(mt * 16 + lo16) * MLDA + kk * 32 + quad * 8];
#pragma unroll
            for (int mt = 0; mt < 4; ++mt)
#pragma unroll
                for (int nt = 0; nt < 2; ++nt)
                    acc[mt][nt] = __builtin_amdgcn_mfma_f32_16x16x32_bf16(
                        a[mt], bfr[nt][kk], acc[mt][nt], 0, 0, 0);
        }
#pragma unroll
        for (int mt = 0; mt < 4; ++mt)
#pragma unroll
            for (int r = 0; r < 4; ++r) {
                float z0 = acc[mt][0][r] + c0;
                z0 = z0 > 0.f ? z0 : LRELU * z0;
                float z1 = acc[mt][1][r] + c1;
                z1 = z1 > 0.f ? z1 : LRELU * z1;
                float s = w0 * z0 + w1 * z1;
                s = xorReduce16(s);
                if (lo16 == 0) swave[w][mt * 16 + quad * 4 + r] = s;
            }
        __syncthreads();
        if (tid < 64)
            lgL[tid] = san(swave[0][tid] + swave[1][tid] + swave[2][tid] + swave[3][tid]);
        __syncthreads();
#pragma unroll
        for (int it = 0; it < 16; ++it) {
            int idx = tid + 256 * it;
            int nl = idx >> 7, h = idx & 127;
            int node = tile * 32 + nl;
            if (node < NN) {
                float g0 = lgL[2 * nl], g1 = lgL[2 * nl + 1];
                float mm = fmaxf(g0, g1);
                float e0 = __expf(g0 - mm), e1 = __expf(g1 - mm);
                float inv = __builtin_amdgcn_rcpf(e0 + e1);
                float xv = ldf(x, node * HID + h, fx);
                float sv = b2f(smb[node * HID + h]);
                stf(outx, node * HID + h, san((e0 * xv + e1 * sv) * inv), fo);
            }
        }
    }
}

// ---------------------------------------------------------------- CSR build
__global__ void count_kernel(const int* __restrict__ ei, const int* __restrict__ flags,
                             int* __restrict__ counts) {
    const int is64e = flags[4];
    for (int e = blockIdx.x * blockDim.x + threadIdx.x; e < NE; e += gridDim.x * blockDim.x) {
        int tail = clampi(idx_at(ei, NE + e, is64e), NN);
        atomicAdd(&counts[tail], 1);
    }
}

// 3-phase multi-block exclusive scan over counts[NN]
__global__ void scan_phase1(const int* __restrict__ counts, int* __restrict__ offs,
                            int* __restrict__ bsum) {
    __shared__ int buf[256];
    int t = threadIdx.x;
    int i = blockIdx.x * 256 + t;
    int v = (i < NN) ? counts[i] : 0;
    buf[t] = v;
    __syncthreads();
    for (int off = 1; off < 256; off <<= 1) {
        int add = (t >= off) ? buf[t - off] : 0;
        __syncthreads();
        buf[t] += add;
        __syncthreads();
    }
    if (i < NN) offs[i] = buf[t] - v;  // intra-block exclusive
    if (t == 255) bsum[blockIdx.x] = buf[255];
}

__global__ void scan_phase2(int* __restrict__ bsum, int* __restrict__ bexc) {
    __shared__ int buf[256];
    int t = threadIdx.x;
    int v = (t < SCAN_BLOCKS) ? bsum[t] : 0;
    buf[t] = v;
    __syncthreads();
    for (int off = 1; off < 256; off <<= 1) {
        int add = (t >= off) ? buf[t - off] : 0;
        __syncthreads();
        buf[t] += add;
        __syncthreads();
    }
    if (t < SCAN_BLOCKS) bexc[t] = buf[t] - v;
    if (t == 255) bexc[SCAN_BLOCKS] = buf[255];  // grand total
}

__global__ void scan_phase3(int* __restrict__ offs, int* __restrict__ cursor,
                            const int* __restrict__ bexc) {
    int i = blockIdx.x * 256 + threadIdx.x;
    if (i < NN) {
        int v = offs[i] + bexc[blockIdx.x];
        offs[i] = v;
        cursor[i] = v;
    }
    if (i == 0) offs[NN] = bexc[SCAN_BLOCKS];
}

__global__ void scatter_kernel(const int* __restrict__ ei, const int* __restrict__ ea,
                               const int* __restrict__ flags,
                               int* __restrict__ cursor, unsigned int* __restrict__ hrcsr) {
    const int is64e = flags[4], is64a = flags[5];
    for (int e = blockIdx.x * blockDim.x + threadIdx.x; e < NE; e += gridDim.x * blockDim.x) {
        int tail = clampi(idx_at(ei, NE + e, is64e), NN);
        int head = clampi(idx_at(ei, e, is64e), NN);
        int rel = clampi(idx_at(ea, e, is64a), NR);
        int p = atomicAdd(&cursor[tail], 1);
        if (p >= 0 && p < NE)
            hrcsr[p] = (unsigned int)head | ((unsigned int)rel << 16);
    }
}

// ---------------------------------------------------------------- node softmax + aggregation
__global__ __launch_bounds__(256, 8) void node_aggr_kernel(
        const bf16* __restrict__ Xmb, const bf16* __restrict__ Rmb,
        const int* __restrict__ offs, const unsigned int* __restrict__ hrcsr,
        const float* __restrict__ ccsr, bf16* __restrict__ smb) {
    int tid = threadIdx.x;
    int sub = tid >> 6;
    int lane = tid & 63;
    int node = blockIdx.x * 4 + sub;
    if (node >= NN) return;
    int s = offs[node], en = offs[node + 1];

    float m = -INFINITY;
    for (int i = s + lane; i < en; i += 64) m = fmaxf(m, ccsr[i]);
    m = waveMax(m);
    float lsum = 0.f;
    for (int i = s + lane; i < en; i += 64) lsum += __expf(ccsr[i] - m);
    lsum = waveSum(lsum);
    float inv = 1.f / (lsum + 1e-16f);

    const int col = lane * 2;
    float acc0 = 0.f, acc1 = 0.f;
    int i = s;
    for (; i + 2 <= en; i += 2) {
        unsigned int hr0 = hrcsr[i], hr1 = hrcsr[i + 1];
        float wg0 = __expf(ccsr[i] - m), wg1 = __expf(ccsr[i + 1] - m);
        unsigned int xv0 = *(const unsigned int*)&Xmb[(hr0 & 0xffffu) * HID + col];
        unsigned int rv0 = *(const unsigned int*)&Rmb[(hr0 >> 16) * HID + col];
        unsigned int xv1 = *(const unsigned int*)&Xmb[(hr1 & 0xffffu) * HID + col];
        unsigned int rv1 = *(const unsigned int*)&Rmb[(hr1 >> 16) * HID + col];
        acc0 += wg0 * ftanh(bflo(xv0) + bflo(rv0)) + wg1 * ftanh(bflo(xv1) + bflo(rv1));
        acc1 += wg0 * ftanh(bfhi(xv0) + bfhi(rv0)) + wg1 * ftanh(bfhi(xv1) + bfhi(rv1));
    }
    if (i < en) {
        unsigned int hr0 = hrcsr[i];
        float wg0 = __expf(ccsr[i] - m);
        unsigned int xv0 = *(const unsigned int*)&Xmb[(hr0 & 0xffffu) * HID + col];
        unsigned int rv0 = *(const unsigned int*)&Rmb[(hr0 >> 16) * HID + col];
        acc0 += wg0 * ftanh(bflo(xv0) + bflo(rv0));
        acc1 += wg0 * ftanh(bfhi(xv0) + bfhi(rv0));
    }
    *(unsigned int*)&smb[node * HID + col] = packbf2(san(acc0 * inv), san(acc1 * inv));
}

extern "C" void kernel_launch(void* const* d_in, const int* in_sizes, int n_in,
                              void* d_out, int out_size, void* d_ws, size_t ws_size,
                              hipStream_t stream) {
    const void* x     = d_in[0];
    const void* r     = d_in[1];
    const void* qc    = d_in[2];
    const void* fq    = d_in[3];
    const int*  ei    = (const int*)d_in[4];
    const int*  ea    = (const int*)d_in[5];
    const void* Wmess = d_in[6];
    const void* bmess = d_in[7];
    const void* Wmatt = d_in[8];
    const void* bmatt = d_in[9];
    const void* maw   = d_in[10];
    const void* Wxatt = d_in[11];
    const void* bxatt = d_in[12];
    const void* xaw   = d_in[13];
    const void* gamma = d_in[14];
    const void* beta  = d_in[15];

    int*          flags  = (int*)d_ws;                       // 16
    int*          counts = flags + 16;                       // NN
    int*          offs   = counts + NN;                      // NN+1
    int*          cursor = offs + NN + 1;                    // NN (+3 pad)
    int*          bsum   = cursor + NN + 3;                  // 256
    int*          bexc   = bsum + 256;                       // 256+1 (+3 pad)
    unsigned int* hrcsr  = (unsigned int*)(bexc + 260);      // NE
    float*        ccsr   = (float*)(hrcsr + NE);             // NE
    float*        rnorm  = ccsr + NE;                        // NR*HID
    float*        stats  = rnorm + (size_t)NR * HID;         // 2*HID
    float*        cmatt  = stats + 2 * HID;                  // HID
    float*        cxatt  = cmatt + HID;                      // HID
    bf16*         Rmb    = (bf16*)(cxatt + HID);             // NR*HID
    bf16*         Xmb    = Rmb + (size_t)NR * HID;           // NN*HID
    bf16*         smb    = Xmb + (size_t)NN * HID;           // NN*HID

    hipMemsetAsync(counts, 0, NN * sizeof(int), stream);

    DetectArr da;
    const void* ps[16] = {x, r, qc, fq, ei, ea, Wmess, bmess, Wmatt, bmatt, maw,
                          Wxatt, bxatt, xaw, gamma, beta};
    int szs[16] = {NN * HID, NR * HID, HID, HID, 2 * NE, NE, 2 * HID * HID, HID,
                   2 * HID * HID, HID, HID, 2 * HID * HID, HID, HID, HID, HID};
    for (int i = 0; i < 16; ++i) {
        da.p[i] = ps[i];
        da.sz[i] = szs[i];
        da.kind[i] = (i == 4 || i == 5) ? 1 : 0;
    }
    detect_all<<<16, 64, 0, stream>>>(da, flags);

    bn_stats<<<HID, 256, 0, stream>>>(r, flags, stats);
    bn_apply<<<(NR * HID + 255) / 256, 256, 0, stream>>>(r, gamma, beta, flags, stats,
                                                         rnorm, d_out);
    precomp_kernel<<<1, HID, 0, stream>>>(Wmatt, bmatt, qc, Wxatt, bxatt, fq, flags,
                                          cmatt, cxatt);
    rm_kernel<<<NR, HID, 0, stream>>>(Wmess, bmess, flags, rnorm, Rmb);
    xm_mfma<<<512, 256, 0, stream>>>(x, Wmess, flags, Xmb);
    count_kernel<<<1024, 256, 0, stream>>>(ei, flags, counts);
    scan_phase1<<<SCAN_BLOCKS, 256, 0, stream>>>(counts, offs, bsum);
    scan_phase2<<<1, 256, 0, stream>>>(bsum, bexc);
    scan_phase3<<<SCAN_BLOCKS, 256, 0, stream>>>(offs, cursor, bexc);
    scatter_kernel<<<1024, 256, 0, stream>>>(ei, ea, flags, cursor, hrcsr);
    edge_coeff_mfma<<<1536, 256, 0, stream>>>(Xmb, Rmb, Wmatt, cmatt, maw, hrcsr, flags,
                                              ccsr);
    node_aggr_kernel<<<(NN + 3) / 4, 256, 0, stream>>>(Xmb, Rmb, offs, hrcsr, ccsr, smb);
    gate_mfma<<<512, 256, 0, stream>>>(x, smb, Wxatt, cxatt, xaw, flags, d_out);
}